// Round 1
// 880.401 us; speedup vs baseline: 1.0041x; 1.0041x over previous
//
#include <hip/hip_runtime.h>
#include <hip/hip_bf16.h>

#define N_NODES 100000
#define N_EDGES 3200000
#define F_IN 512
#define NHEAD 8
#define CH1 8
#define F1 64   // NHEAD*CH1
#define C2 7
#define NEG 0.2f
#define NBUCK 391   // dst>>8 : 99999>>8 = 390

typedef __bf16 bf16x8 __attribute__((ext_vector_type(8)));
typedef float  f32x4  __attribute__((ext_vector_type(4)));
typedef unsigned int u32x4 __attribute__((ext_vector_type(4)));

union U4BF8 { u32x4 u; bf16x8 v; };

// load element i of a buffer whose dtype is f32 (mode=1) or bf16 (mode=0)
__device__ __forceinline__ float ldmix(const void* p, size_t i, int f32mode) {
  if (f32mode) return ((const float*)p)[i];
  union { unsigned short u; __bf16 b; } c;
  c.u = ((const unsigned short*)p)[i];
  return (float)c.b;
}

// ---------------- dtype detection: 1 wave -----------------------------------
__global__ void detect_kernel(const unsigned int* __restrict__ x, int* __restrict__ flag) {
  int lane = threadIdx.x & 63;
  unsigned int w = x[lane];
  union { unsigned short u; __bf16 b; } c;
  c.u = (unsigned short)(w & 0xFFFFu);
  float v = (float)c.b;
  bool big = !(fabsf(v) <= 1e6f);   // huge or NaN -> f32 data read as bf16
  unsigned long long m = __ballot(big);
  if (lane == 0) *flag = (m != 0ull) ? 1 : 0;
}

// ---------------- GEMM: h1[N,64] = x[N,512] @ W1[512,64]  (bf16 out) -------
// launch_bounds(256,1): unlock VGPR budget so a full row-tile of x can stay
// in flight (72-VGPR version serialized each tile into ~8-16 dependent
// memory latencies -> VALUBusy 2.6%, 450 GB/s). ROWS=64 per block.
#define G1_ROWS 64
__global__ __launch_bounds__(256, 1) void gemm1_kernel(
    const void* __restrict__ x, const void* __restrict__ W1,
    __bf16* __restrict__ h1, const int* __restrict__ flag)
{
  const int mode = *flag;
  const int lane = threadIdx.x & 63;
  const int wave = threadIdx.x >> 6;
  const int c0   = wave * 16;
  const int m    = lane & 15;
  const int quad = lane >> 4;

  bf16x8 bfrag[16];
#pragma unroll
  for (int t = 0; t < 16; ++t) {
    bf16x8 tv;
#pragma unroll
    for (int j = 0; j < 8; ++j)
      tv[j] = (__bf16)ldmix(W1, (size_t)(32*t + quad*8 + j)*F1 + c0 + m, mode);
    bfrag[t] = tv;
  }

  const int rowBase = blockIdx.x * G1_ROWS;
#pragma unroll 1
  for (int rt = 0; rt < G1_ROWS/16; ++rt) {
    const int r0 = rowBase + rt*16;
    int rowA = r0 + m; if (rowA > N_NODES-1) rowA = N_NODES-1;
    f32x4 acc = {0.f, 0.f, 0.f, 0.f};
    if (mode) {
      const float* xpf = (const float*)x + (size_t)rowA * F_IN + quad*8;
      // half-tile register double-buffer: issue ALL loads of half B before
      // consuming half A, so half-B latency hides under half-A MFMAs.
      f32x4 bufA[16];
#pragma unroll
      for (int t = 0; t < 8; ++t) {
        bufA[2*t]   = *(const f32x4*)(xpf + t*32);
        bufA[2*t+1] = *(const f32x4*)(xpf + t*32 + 4);
      }
      f32x4 bufB[16];
#pragma unroll
      for (int t = 0; t < 8; ++t) {
        bufB[2*t]   = *(const f32x4*)(xpf + (t+8)*32);
        bufB[2*t+1] = *(const f32x4*)(xpf + (t+8)*32 + 4);
      }
#pragma unroll
      for (int t = 0; t < 8; ++t) {
        bf16x8 av;
#pragma unroll
        for (int j = 0; j < 4; ++j) { av[j] = (__bf16)bufA[2*t][j]; av[4+j] = (__bf16)bufA[2*t+1][j]; }
        acc = __builtin_amdgcn_mfma_f32_16x16x32_bf16(av, bfrag[t], acc, 0, 0, 0);
      }
#pragma unroll
      for (int t = 0; t < 8; ++t) {
        bf16x8 av;
#pragma unroll
        for (int j = 0; j < 4; ++j) { av[j] = (__bf16)bufB[2*t][j]; av[4+j] = (__bf16)bufB[2*t+1][j]; }
        acc = __builtin_amdgcn_mfma_f32_16x16x32_bf16(av, bfrag[t+8], acc, 0, 0, 0);
      }
    } else {
      const __bf16* xp = (const __bf16*)x + (size_t)rowA * F_IN + quad*8;
      u32x4 buf[16];
#pragma unroll
      for (int t = 0; t < 16; ++t) buf[t] = *(const u32x4*)(xp + t*32);
#pragma unroll
      for (int t = 0; t < 16; ++t) {
        U4BF8 a;
        a.u = buf[t];
        acc = __builtin_amdgcn_mfma_f32_16x16x32_bf16(a.v, bfrag[t], acc, 0, 0, 0);
      }
    }
#pragma unroll
    for (int j = 0; j < 4; ++j) {
      int row = r0 + quad*4 + j;
      if (row < N_NODES) h1[(size_t)row*F1 + c0 + m] = (__bf16)acc[j];
    }
  }
}

// ---------------- alpha_s1/alpha_d1 [N,8] ----------------------------------
__global__ __launch_bounds__(256) void alpha1_kernel(
    const __bf16* __restrict__ h1,
    const void* __restrict__ a_src, const void* __restrict__ a_dst,
    float* __restrict__ as, float* __restrict__ ad, const int* __restrict__ flag)
{
  const int mode = *flag;
  int i = blockIdx.x * 256 + threadIdx.x;   // n*8+h
  if (i >= N_NODES * NHEAD) return;
  int h = i & 7;
  const __bf16* hp = h1 + (size_t)(i >> 3) * F1 + h * CH1;
  float s = 0.f, d = 0.f;
#pragma unroll
  for (int c = 0; c < CH1; ++c) {
    float hv = (float)hp[c];
    s += hv * ldmix(a_src, h*CH1 + c, mode);
    d += hv * ldmix(a_dst, h*CH1 + c, mode);
  }
  as[i] = s; ad[i] = d;
}

// ---------------- CSR build, two-level binned -------------------------------
// Phase A: bucket histogram (LDS-aggregated)
__global__ __launch_bounds__(256) void buckhist_kernel(
    const int* __restrict__ ei, int* __restrict__ bh)
{
  __shared__ int h[NBUCK];
  for (int i = threadIdx.x; i < NBUCK; i += 256) h[i] = 0;
  __syncthreads();
  int start = blockIdx.x * 4096;
  for (int i = threadIdx.x; i < 4096; i += 256) {
    int e = start + i;
    if (e < N_EDGES) atomicAdd(&h[ei[N_EDGES + e] >> 8], 1);
  }
  __syncthreads();
  for (int i = threadIdx.x; i < NBUCK; i += 256) {
    int c = h[i];
    if (c) atomicAdd(&bh[i], c);
  }
}

// Phase B-scan: exclusive scan of 391 bucket counts -> bases + cursors
__global__ __launch_bounds__(512) void buckscan_kernel(
    const int* __restrict__ bh, int* __restrict__ bb, int* __restrict__ bcur)
{
  __shared__ int s[512];
  int t = threadIdx.x;
  int v = (t < NBUCK) ? bh[t] : 0;
  s[t] = v;
  __syncthreads();
#pragma unroll
  for (int o = 1; o < 512; o <<= 1) {
    int u = (t >= o) ? s[t - o] : 0;
    __syncthreads();
    s[t] += u;
    __syncthreads();
  }
  if (t < NBUCK) { bb[t] = s[t] - v; bcur[t] = s[t] - v; }
  if (t == NBUCK - 1) bb[NBUCK] = s[t];
}

// Phase B: scatter packed (src<<8 | dst&255) into bucket-ordered `pairs`.
// Per-block LDS histogram -> one global range-claim per bucket -> dense writes.
#define CHB 16384
__global__ __launch_bounds__(256) void buckscatter_kernel(
    const int* __restrict__ ei, int* __restrict__ bcur, int* __restrict__ pairs)
{
  __shared__ int h[NBUCK];
  __shared__ int base[NBUCK];
  for (int i = threadIdx.x; i < NBUCK; i += 256) h[i] = 0;
  __syncthreads();
  int start = blockIdx.x * CHB;
  for (int i = threadIdx.x; i < CHB; i += 256) {
    int e = start + i;
    if (e < N_EDGES) atomicAdd(&h[ei[N_EDGES + e] >> 8], 1);
  }
  __syncthreads();
  for (int i = threadIdx.x; i < NBUCK; i += 256) {
    int c = h[i];
    base[i] = c ? atomicAdd(&bcur[i], c) : 0;
    h[i] = 0;
  }
  __syncthreads();
  for (int i = threadIdx.x; i < CHB; i += 256) {
    int e = start + i;
    if (e < N_EDGES) {
      int dst = ei[N_EDGES + e];
      int src = ei[e];
      int b = dst >> 8;
      int pos = base[b] + atomicAdd(&h[b], 1);
      pairs[pos] = (src << 8) | (dst & 255);
    }
  }
}

// Phase C: one block per bucket: LDS per-dst hist + scan -> off[] AND sorted[]
__global__ __launch_bounds__(256) void csrbuild_kernel(
    const int* __restrict__ bb, const int* __restrict__ pairs,
    int* __restrict__ off, int* __restrict__ sorted)
{
  __shared__ int cnt[256];
  __shared__ int scan[256];
  int b = blockIdx.x;
  int lo = bb[b], hi = bb[b+1];
  int t = threadIdx.x;
  cnt[t] = 0;
  __syncthreads();
  for (int i = lo + t; i < hi; i += 256)
    atomicAdd(&cnt[pairs[i] & 255], 1);
  __syncthreads();
  int v = cnt[t];
  scan[t] = v;
  __syncthreads();
#pragma unroll
  for (int o = 1; o < 256; o <<= 1) {
    int u = (t >= o) ? scan[t - o] : 0;
    __syncthreads();
    scan[t] += u;
    __syncthreads();
  }
  int excl = scan[t] - v;
  int node = b * 256 + t;
  if (node < N_NODES) off[node] = lo + excl;
  if (b == 0 && t == 0) off[N_NODES] = N_EDGES;
  __syncthreads();
  cnt[t] = excl;   // cursor
  __syncthreads();
  for (int i = lo + t; i < hi; i += 256) {
    int p = pairs[i];
    int w = lo + atomicAdd(&cnt[p & 255], 1);
    sorted[w] = p >> 8;
  }
}

// ---------------- layer-1 aggregate: one wave per dst (gather, no atomics) --
__global__ __launch_bounds__(256) void aggregate1_kernel(
    const int* __restrict__ off, const int* __restrict__ sorted,
    const __bf16* __restrict__ h1,
    const float* __restrict__ as, const float* __restrict__ ad,
    const void* __restrict__ b1, __bf16* __restrict__ out1,
    const int* __restrict__ flag)
{
  const int mode = *flag;
  const int lane = threadIdx.x & 63;
  int n = blockIdx.x * 4 + (threadIdx.x >> 6);
  if (n >= N_NODES) return;
  const int h = lane >> 3;
  const float ad_h = ad[n*NHEAD + h];

  // self-loop
  float e0 = as[n*NHEAD + h] + ad_h;
  e0 = e0 > 0.f ? e0 : NEG * e0;
  float w0 = __expf(e0);
  float acc = w0 * (float)h1[(size_t)n*F1 + lane];
  float den = w0;

  const int begin = off[n];
  const int cnt   = off[n+1] - begin;
  for (int base = 0; base < cnt; base += 64) {
    int idx = base + lane;
    int sv = (idx < cnt) ? sorted[begin + idx] : 0;
    int jmax = cnt - base; if (jmax > 64) jmax = 64;
    for (int j = 0; j < jmax; ++j) {
      int src = __shfl(sv, j);
      float e = as[src*NHEAD + h] + ad_h;
      e = e > 0.f ? e : NEG * e;
      float w = __expf(e);
      acc += w * (float)h1[(size_t)src*F1 + lane];
      den += w;
    }
  }
  out1[(size_t)n*F1 + lane] = (__bf16)(acc / den + ldmix(b1, lane, mode));
}

// ---------------- h2 = out1 @ W2 (padded to 8), alpha2 ----------------------
__global__ __launch_bounds__(256) void h2_kernel(
    const __bf16* __restrict__ out1, const void* __restrict__ W2,
    const void* __restrict__ a_src2, const void* __restrict__ a_dst2,
    float* __restrict__ h2p, float* __restrict__ as2, float* __restrict__ ad2,
    const int* __restrict__ flag)
{
  const int mode = *flag;
  __shared__ float W2f[F1*C2];
  __shared__ float asw[C2], adw[C2];
  int t = threadIdx.x;
  for (int i = t; i < F1*C2; i += 256) W2f[i] = ldmix(W2, i, mode);
  if (t < C2) { asw[t] = ldmix(a_src2, t, mode); adw[t] = ldmix(a_dst2, t, mode); }
  __syncthreads();
  int n = blockIdx.x * 256 + t;
  if (n >= N_NODES) return;
  float r[F1];
  const __bf16* row = out1 + (size_t)n * F1;
#pragma unroll
  for (int j = 0; j < F1; ++j) r[j] = (float)row[j];
  float s = 0.f, d = 0.f;
#pragma unroll
  for (int c = 0; c < C2; ++c) {
    float acc = 0.f;
#pragma unroll
    for (int j = 0; j < F1; ++j) acc += r[j] * W2f[j*C2 + c];
    h2p[(size_t)n*8 + c] = acc;
    s += acc * asw[c]; d += acc * adw[c];
  }
  h2p[(size_t)n*8 + 7] = 0.f;
  as2[n] = s; ad2[n] = d;
}

// ---------------- layer-2 aggregate: 8 dsts per wave, 8 lanes each ----------
__global__ __launch_bounds__(256) void aggregate2_kernel(
    const int* __restrict__ off, const int* __restrict__ sorted,
    const float* __restrict__ h2p,
    const float* __restrict__ as2, const float* __restrict__ ad2,
    float* __restrict__ logitsP)
{
  const int lane = threadIdx.x & 63;
  const int c    = lane & 7;
  long long wid  = (long long)blockIdx.x * 4 + (threadIdx.x >> 6);
  int n = (int)(wid * 8 + (lane >> 3));
  bool valid = (n < N_NODES);
  if (!valid) n = N_NODES - 1;
  const float ad_n = ad2[n];

  float e0 = as2[n] + ad_n;
  e0 = e0 > 0.f ? e0 : NEG * e0;
  float w0 = __expf(e0);
  float acc = w0 * h2p[(size_t)n*8 + c];   // c==7 slot is 0
  float den = w0;

  const int begin = off[n];
  const int cnt   = off[n+1] - begin;
  for (int base = 0; base < cnt; base += 8) {
    int idx = base + c;
    int sv = (idx < cnt) ? sorted[begin + idx] : 0;
#pragma unroll
    for (int j = 0; j < 8; ++j) {
      if (base + j < cnt) {
        int src = __shfl(sv, j, 8);
        float e = as2[src] + ad_n;
        e = e > 0.f ? e : NEG * e;
        float w = __expf(e);
        acc += w * h2p[(size_t)src*8 + c];
        den += w;
      }
    }
  }
  if (valid) logitsP[(size_t)n*8 + c] = acc / den;
}

// ---------------- final: + b2, log_softmax -> out ---------------------------
__global__ __launch_bounds__(256) void out_kernel(
    const float* __restrict__ logitsP, const void* __restrict__ b2,
    void* __restrict__ out, const int* __restrict__ flag)
{
  const int mode = *flag;
  int n = blockIdx.x * 256 + threadIdx.x;
  if (n >= N_NODES) return;
  float v[C2];
  float m = -1e30f;
#pragma unroll
  for (int c = 0; c < C2; ++c) {
    v[c] = logitsP[(size_t)n*8 + c] + ldmix(b2, c, mode);
    m = fmaxf(m, v[c]);
  }
  float s = 0.f;
#pragma unroll
  for (int c = 0; c < C2; ++c) s += __expf(v[c] - m);
  float lse = m + __logf(s);
  if (mode) {
    float* op = (float*)out;
#pragma unroll
    for (int c = 0; c < C2; ++c) op[(size_t)n*C2 + c] = v[c] - lse;
  } else {
    __hip_bfloat16* op = (__hip_bfloat16*)out;
#pragma unroll
    for (int c = 0; c < C2; ++c) op[(size_t)n*C2 + c] = __float2bfloat16(v[c] - lse);
  }
}

extern "C" void kernel_launch(void* const* d_in, const int* in_sizes, int n_in,
                              void* d_out, int out_size, void* d_ws, size_t ws_size,
                              hipStream_t stream)
{
  const void* x    = d_in[0];
  const int*  ei   = (const int*)d_in[1];
  const void* W1   = d_in[2];
  const void* as1w = d_in[3];
  const void* ad1w = d_in[4];
  const void* b1   = d_in[5];
  const void* W2   = d_in[6];
  const void* as2w = d_in[7];
  const void* ad2w = d_in[8];
  const void* b2   = d_in[9];

  // ---- workspace layout (float units), total 11.45M floats = 45.8 MB ----
  int*   flag = (int*)d_ws;
  float* ws   = (float*)d_ws + 16;

  float*  A      = ws;                      // region A: [0, 3.2M)
  __bf16* h1b    = (__bf16*)A;              // 6.4M bf16 (dead after aggregate1)
  float*  h2p    = A;                       // 0.8M (aliases dead h1b)
  float*  as2    = A + 800000;              // 0.1M
  float*  ad2    = A + 900000;              // 0.1M
  float*  logitsP= A + 1000000;             // 0.8M (ends 1.8M < 3.2M)

  float*  as1    = ws + 3200000;            // [3.2M, 4.0M)
  float*  ad1    = ws + 4000000;            // [4.0M, 4.8M)
  __bf16* out1   = (__bf16*)(ws + 4800000); // [4.8M, 8.0M) : 6.4M bf16
  int*    pairs  = (int*)(ws + 4800000);    // 3.2M ints, aliases out1 (dead
                                            //   until aggregate1 writes it;
                                            //   pairs dead after csrbuild)
  int*    off    = (int*)(ws + 8000000);    // 100001 ints
  int*    bh     = (int*)(ws + 8110000);    // 391 ints (bucket hist)
  int*    bb     = (int*)(ws + 8112000);    // 392 ints (bucket base)
  int*    bcur   = (int*)(ws + 8114000);    // 391 ints (bucket cursor)
  int*    sorted = (int*)(ws + 8250000);    // [8.25M, 11.45M) : 3.2M ints

  detect_kernel<<<1, 64, 0, stream>>>((const unsigned int*)x, flag);
  hipMemsetAsync(bh, 0, NBUCK * sizeof(int), stream);

  gemm1_kernel<<<(N_NODES + G1_ROWS - 1) / G1_ROWS, 256, 0, stream>>>(x, W1, h1b, flag);
  alpha1_kernel<<<(N_NODES * NHEAD + 255) / 256, 256, 0, stream>>>(h1b, as1w, ad1w, as1, ad1, flag);

  // CSR build (two-level binned; dst-major order == CSR order)
  buckhist_kernel<<<(N_EDGES + 4095) / 4096, 256, 0, stream>>>(ei, bh);
  buckscan_kernel<<<1, 512, 0, stream>>>(bh, bb, bcur);
  buckscatter_kernel<<<(N_EDGES + CHB - 1) / CHB, 256, 0, stream>>>(ei, bcur, pairs);
  csrbuild_kernel<<<NBUCK, 256, 0, stream>>>(bb, pairs, off, sorted);

  aggregate1_kernel<<<(N_NODES + 3) / 4, 256, 0, stream>>>(
      off, sorted, h1b, as1, ad1, b1, out1, flag);

  h2_kernel<<<(N_NODES + 255) / 256, 256, 0, stream>>>(out1, W2, as2w, ad2w, h2p, as2, ad2, flag);

  aggregate2_kernel<<<(N_NODES/8 + 3) / 4 + 1, 256, 0, stream>>>(
      off, sorted, h2p, as2, ad2, logitsP);

  out_kernel<<<(N_NODES + 255) / 256, 256, 0, stream>>>(logitsP, b2, d_out, flag);
}

// Round 2
// 843.845 us; speedup vs baseline: 1.0476x; 1.0433x over previous
//
#include <hip/hip_runtime.h>
#include <hip/hip_bf16.h>

#define N_NODES 100000
#define N_EDGES 3200000
#define F_IN 512
#define NHEAD 8
#define CH1 8
#define F1 64   // NHEAD*CH1
#define C2 7
#define NEG 0.2f
#define NBUCK 391   // dst>>8 : 99999>>8 = 390

typedef __bf16 bf16x8 __attribute__((ext_vector_type(8)));
typedef float  f32x4  __attribute__((ext_vector_type(4)));
typedef unsigned int u32x4 __attribute__((ext_vector_type(4)));

union U4BF8 { u32x4 u; bf16x8 v; };

// load element i of a buffer whose dtype is f32 (mode=1) or bf16 (mode=0)
__device__ __forceinline__ float ldmix(const void* p, size_t i, int f32mode) {
  if (f32mode) return ((const float*)p)[i];
  union { unsigned short u; __bf16 b; } c;
  c.u = ((const unsigned short*)p)[i];
  return (float)c.b;
}

// ---------------- dtype detection: 1 wave -----------------------------------
__global__ void detect_kernel(const unsigned int* __restrict__ x, int* __restrict__ flag) {
  int lane = threadIdx.x & 63;
  unsigned int w = x[lane];
  union { unsigned short u; __bf16 b; } c;
  c.u = (unsigned short)(w & 0xFFFFu);
  float v = (float)c.b;
  bool big = !(fabsf(v) <= 1e6f);   // huge or NaN -> f32 data read as bf16
  unsigned long long m = __ballot(big);
  if (lane == 0) *flag = (m != 0ull) ? 1 : 0;
}

// ---------------- GEMM: h1[N,64] = x[N,512] @ W1[512,64]  (bf16 out) -------
// v2: LDS-staged tiled GEMM. Round-0/1 showed reg-path loads serialize into
// full HBM latencies (T_chain ~16us/row-tile, VALUBusy 3.5%). Fix: DMA
// global_load_lds (width 16, no VGPR round-trip, deep in flight) into a
// double-buffered 64-row x 512B K-chunk tile shared by all 4 waves.
// XOR granule swizzle (both sides: pre-swizzled source + swizzled ds_read)
// kills the 16-way bank conflict of the 512B-stride row reads.
#define G1_ROWS 64

__device__ __forceinline__ int g1_swz(int g, int row) {
  return (g & 0x18) | ((g ^ row) & 7);
}

// stage one 32KB chunk: granule G = (i*4+wave)*64+lane; LDS dest linear,
// global source pre-swizzled so lds[row][g'] = x[row][swz(g',row)].
__device__ __forceinline__ void g1_stage(const char* xb, char* ldsbuf, int rowBase,
                                         int cByte, int wl, int lane, int rowBytes)
{
#pragma unroll
  for (int i = 0; i < 8; ++i) {
    int G   = ((i * 4 + wl) << 6) + lane;
    int row = G >> 5;
    int gp  = G & 31;
    int g   = g1_swz(gp, row);
    int grow = rowBase + row; if (grow > N_NODES - 1) grow = N_NODES - 1;
    const char* src = xb + (size_t)grow * rowBytes + cByte + g * 16;
    __builtin_amdgcn_global_load_lds(
        (const __attribute__((address_space(1))) void*)src,
        (__attribute__((address_space(3))) void*)(ldsbuf + ((i * 4 + wl) << 10)),
        16, 0, 0);
  }
}

// compute chunk C (f32 data in LDS): 4 row-tiles x 4 k-steps
__device__ __forceinline__ void g1_comp_f32(const char* ldsbuf, const bf16x8* bfrag,
                                            f32x4* acc, int C, int m, int q)
{
#pragma unroll
  for (int rt = 0; rt < 4; ++rt) {
    const int row = rt * 16 + m;
    const char* rbase = ldsbuf + row * 512;
#pragma unroll
    for (int ks = 0; ks < 4; ++ks) {
      int g0 = ks * 8 + q * 2;
      int s0 = g1_swz(g0, row);
      int s1 = g1_swz(g0 + 1, row);
      f32x4 lo = *(const f32x4*)(rbase + s0 * 16);
      f32x4 hi = *(const f32x4*)(rbase + s1 * 16);
      bf16x8 av;
#pragma unroll
      for (int j = 0; j < 4; ++j) { av[j] = (__bf16)lo[j]; av[4 + j] = (__bf16)hi[j]; }
      acc[rt] = __builtin_amdgcn_mfma_f32_16x16x32_bf16(av, bfrag[C * 4 + ks], acc[rt], 0, 0, 0);
    }
  }
}

// compute chunk C (bf16 data in LDS): 4 row-tiles x 8 k-steps
__device__ __forceinline__ void g1_comp_bf16(const char* ldsbuf, const bf16x8* bfrag,
                                             f32x4* acc, int C, int m, int q)
{
#pragma unroll
  for (int rt = 0; rt < 4; ++rt) {
    const int row = rt * 16 + m;
    const char* rbase = ldsbuf + row * 512;
#pragma unroll
    for (int ks = 0; ks < 8; ++ks) {
      int g0 = ks * 4 + q;
      int s0 = g1_swz(g0, row);
      U4BF8 a;
      a.u = *(const u32x4*)(rbase + s0 * 16);
      acc[rt] = __builtin_amdgcn_mfma_f32_16x16x32_bf16(a.v, bfrag[C * 8 + ks], acc[rt], 0, 0, 0);
    }
  }
}

__global__ __launch_bounds__(256, 2) void gemm1_kernel(
    const void* __restrict__ x, const void* __restrict__ W1,
    __bf16* __restrict__ h1, const int* __restrict__ flag)
{
  __shared__ __align__(128) char lds[2][32768];
  const int mode = *flag;
  const int lane = threadIdx.x & 63;
  const int wl   = threadIdx.x >> 6;
  const int c0   = wl * 16;
  const int m    = lane & 15;
  const int q    = lane >> 4;

  const int rowBase = blockIdx.x * G1_ROWS;
  const char* xb = (const char*)x;
  const int RB = mode ? 2048 : 1024;

  // issue first chunk's DMA before the (slow, scattered) W1 fragment loads
  g1_stage(xb, lds[0], rowBase, 0, wl, lane, RB);

  bf16x8 bfrag[16];
#pragma unroll
  for (int t = 0; t < 16; ++t) {
    bf16x8 tv;
#pragma unroll
    for (int j = 0; j < 8; ++j)
      tv[j] = (__bf16)ldmix(W1, (size_t)(32 * t + q * 8 + j) * F1 + c0 + m, mode);
    bfrag[t] = tv;
  }

  f32x4 acc[4];
#pragma unroll
  for (int rt = 0; rt < 4; ++rt) acc[rt] = (f32x4){0.f, 0.f, 0.f, 0.f};

  if (mode) {
    // 4 chunks of 128 f32 (512B/row), double-buffered
    __syncthreads();
    g1_stage(xb, lds[1], rowBase, 512, wl, lane, RB);
    g1_comp_f32(lds[0], bfrag, acc, 0, m, q);
    __syncthreads();
    g1_stage(xb, lds[0], rowBase, 1024, wl, lane, RB);
    g1_comp_f32(lds[1], bfrag, acc, 1, m, q);
    __syncthreads();
    g1_stage(xb, lds[1], rowBase, 1536, wl, lane, RB);
    g1_comp_f32(lds[0], bfrag, acc, 2, m, q);
    __syncthreads();
    g1_comp_f32(lds[1], bfrag, acc, 3, m, q);
  } else {
    // 2 chunks of 256 bf16 (512B/row), double-buffered
    __syncthreads();
    g1_stage(xb, lds[1], rowBase, 512, wl, lane, RB);
    g1_comp_bf16(lds[0], bfrag, acc, 0, m, q);
    __syncthreads();
    g1_comp_bf16(lds[1], bfrag, acc, 1, m, q);
  }

#pragma unroll
  for (int rt = 0; rt < 4; ++rt) {
#pragma unroll
    for (int j = 0; j < 4; ++j) {
      int row = rowBase + rt * 16 + q * 4 + j;
      if (row < N_NODES) h1[(size_t)row * F1 + c0 + m] = (__bf16)acc[rt][j];
    }
  }
}

// ---------------- alpha_s1/alpha_d1 [N,8] ----------------------------------
__global__ __launch_bounds__(256) void alpha1_kernel(
    const __bf16* __restrict__ h1,
    const void* __restrict__ a_src, const void* __restrict__ a_dst,
    float* __restrict__ as, float* __restrict__ ad, const int* __restrict__ flag)
{
  const int mode = *flag;
  int i = blockIdx.x * 256 + threadIdx.x;   // n*8+h
  if (i >= N_NODES * NHEAD) return;
  int h = i & 7;
  const __bf16* hp = h1 + (size_t)(i >> 3) * F1 + h * CH1;
  float s = 0.f, d = 0.f;
#pragma unroll
  for (int c = 0; c < CH1; ++c) {
    float hv = (float)hp[c];
    s += hv * ldmix(a_src, h*CH1 + c, mode);
    d += hv * ldmix(a_dst, h*CH1 + c, mode);
  }
  as[i] = s; ad[i] = d;
}

// ---------------- CSR build, two-level binned -------------------------------
// Phase A: bucket histogram (LDS-aggregated)
__global__ __launch_bounds__(256) void buckhist_kernel(
    const int* __restrict__ ei, int* __restrict__ bh)
{
  __shared__ int h[NBUCK];
  for (int i = threadIdx.x; i < NBUCK; i += 256) h[i] = 0;
  __syncthreads();
  int start = blockIdx.x * 4096;
  for (int i = threadIdx.x; i < 4096; i += 256) {
    int e = start + i;
    if (e < N_EDGES) atomicAdd(&h[ei[N_EDGES + e] >> 8], 1);
  }
  __syncthreads();
  for (int i = threadIdx.x; i < NBUCK; i += 256) {
    int c = h[i];
    if (c) atomicAdd(&bh[i], c);
  }
}

// Phase B-scan: exclusive scan of 391 bucket counts -> bases + cursors
__global__ __launch_bounds__(512) void buckscan_kernel(
    const int* __restrict__ bh, int* __restrict__ bb, int* __restrict__ bcur)
{
  __shared__ int s[512];
  int t = threadIdx.x;
  int v = (t < NBUCK) ? bh[t] : 0;
  s[t] = v;
  __syncthreads();
#pragma unroll
  for (int o = 1; o < 512; o <<= 1) {
    int u = (t >= o) ? s[t - o] : 0;
    __syncthreads();
    s[t] += u;
    __syncthreads();
  }
  if (t < NBUCK) { bb[t] = s[t] - v; bcur[t] = s[t] - v; }
  if (t == NBUCK - 1) bb[NBUCK] = s[t];
}

// Phase B: scatter packed (src<<8 | dst&255) into bucket-ordered `pairs`.
// Per-block LDS histogram -> one global range-claim per bucket -> dense writes.
#define CHB 16384
__global__ __launch_bounds__(256) void buckscatter_kernel(
    const int* __restrict__ ei, int* __restrict__ bcur, int* __restrict__ pairs)
{
  __shared__ int h[NBUCK];
  __shared__ int base[NBUCK];
  for (int i = threadIdx.x; i < NBUCK; i += 256) h[i] = 0;
  __syncthreads();
  int start = blockIdx.x * CHB;
  for (int i = threadIdx.x; i < CHB; i += 256) {
    int e = start + i;
    if (e < N_EDGES) atomicAdd(&h[ei[N_EDGES + e] >> 8], 1);
  }
  __syncthreads();
  for (int i = threadIdx.x; i < NBUCK; i += 256) {
    int c = h[i];
    base[i] = c ? atomicAdd(&bcur[i], c) : 0;
    h[i] = 0;
  }
  __syncthreads();
  for (int i = threadIdx.x; i < CHB; i += 256) {
    int e = start + i;
    if (e < N_EDGES) {
      int dst = ei[N_EDGES + e];
      int src = ei[e];
      int b = dst >> 8;
      int pos = base[b] + atomicAdd(&h[b], 1);
      pairs[pos] = (src << 8) | (dst & 255);
    }
  }
}

// Phase C: one block per bucket: LDS per-dst hist + scan -> off[] AND sorted[]
__global__ __launch_bounds__(256) void csrbuild_kernel(
    const int* __restrict__ bb, const int* __restrict__ pairs,
    int* __restrict__ off, int* __restrict__ sorted)
{
  __shared__ int cnt[256];
  __shared__ int scan[256];
  int b = blockIdx.x;
  int lo = bb[b], hi = bb[b+1];
  int t = threadIdx.x;
  cnt[t] = 0;
  __syncthreads();
  for (int i = lo + t; i < hi; i += 256)
    atomicAdd(&cnt[pairs[i] & 255], 1);
  __syncthreads();
  int v = cnt[t];
  scan[t] = v;
  __syncthreads();
#pragma unroll
  for (int o = 1; o < 256; o <<= 1) {
    int u = (t >= o) ? scan[t - o] : 0;
    __syncthreads();
    scan[t] += u;
    __syncthreads();
  }
  int excl = scan[t] - v;
  int node = b * 256 + t;
  if (node < N_NODES) off[node] = lo + excl;
  if (b == 0 && t == 0) off[N_NODES] = N_EDGES;
  __syncthreads();
  cnt[t] = excl;   // cursor
  __syncthreads();
  for (int i = lo + t; i < hi; i += 256) {
    int p = pairs[i];
    int w = lo + atomicAdd(&cnt[p & 255], 1);
    sorted[w] = p >> 8;
  }
}

// ---------------- layer-1 aggregate: one wave per dst (gather, no atomics) --
__global__ __launch_bounds__(256) void aggregate1_kernel(
    const int* __restrict__ off, const int* __restrict__ sorted,
    const __bf16* __restrict__ h1,
    const float* __restrict__ as, const float* __restrict__ ad,
    const void* __restrict__ b1, __bf16* __restrict__ out1,
    const int* __restrict__ flag)
{
  const int mode = *flag;
  const int lane = threadIdx.x & 63;
  int n = blockIdx.x * 4 + (threadIdx.x >> 6);
  if (n >= N_NODES) return;
  const int h = lane >> 3;
  const float ad_h = ad[n*NHEAD + h];

  // self-loop
  float e0 = as[n*NHEAD + h] + ad_h;
  e0 = e0 > 0.f ? e0 : NEG * e0;
  float w0 = __expf(e0);
  float acc = w0 * (float)h1[(size_t)n*F1 + lane];
  float den = w0;

  const int begin = off[n];
  const int cnt   = off[n+1] - begin;
  for (int base = 0; base < cnt; base += 64) {
    int idx = base + lane;
    int sv = (idx < cnt) ? sorted[begin + idx] : 0;
    int jmax = cnt - base; if (jmax > 64) jmax = 64;
    for (int j = 0; j < jmax; ++j) {
      int src = __shfl(sv, j);
      float e = as[src*NHEAD + h] + ad_h;
      e = e > 0.f ? e : NEG * e;
      float w = __expf(e);
      acc += w * (float)h1[(size_t)src*F1 + lane];
      den += w;
    }
  }
  out1[(size_t)n*F1 + lane] = (__bf16)(acc / den + ldmix(b1, lane, mode));
}

// ---------------- h2 = out1 @ W2 (padded to 8), alpha2 ----------------------
__global__ __launch_bounds__(256) void h2_kernel(
    const __bf16* __restrict__ out1, const void* __restrict__ W2,
    const void* __restrict__ a_src2, const void* __restrict__ a_dst2,
    float* __restrict__ h2p, float* __restrict__ as2, float* __restrict__ ad2,
    const int* __restrict__ flag)
{
  const int mode = *flag;
  __shared__ float W2f[F1*C2];
  __shared__ float asw[C2], adw[C2];
  int t = threadIdx.x;
  for (int i = t; i < F1*C2; i += 256) W2f[i] = ldmix(W2, i, mode);
  if (t < C2) { asw[t] = ldmix(a_src2, t, mode); adw[t] = ldmix(a_dst2, t, mode); }
  __syncthreads();
  int n = blockIdx.x * 256 + t;
  if (n >= N_NODES) return;
  float r[F1];
  const __bf16* row = out1 + (size_t)n * F1;
#pragma unroll
  for (int j = 0; j < F1; ++j) r[j] = (float)row[j];
  float s = 0.f, d = 0.f;
#pragma unroll
  for (int c = 0; c < C2; ++c) {
    float acc = 0.f;
#pragma unroll
    for (int j = 0; j < F1; ++j) acc += r[j] * W2f[j*C2 + c];
    h2p[(size_t)n*8 + c] = acc;
    s += acc * asw[c]; d += acc * adw[c];
  }
  h2p[(size_t)n*8 + 7] = 0.f;
  as2[n] = s; ad2[n] = d;
}

// ---------------- layer-2 aggregate: 8 dsts per wave, 8 lanes each ----------
__global__ __launch_bounds__(256) void aggregate2_kernel(
    const int* __restrict__ off, const int* __restrict__ sorted,
    const float* __restrict__ h2p,
    const float* __restrict__ as2, const float* __restrict__ ad2,
    float* __restrict__ logitsP)
{
  const int lane = threadIdx.x & 63;
  const int c    = lane & 7;
  long long wid  = (long long)blockIdx.x * 4 + (threadIdx.x >> 6);
  int n = (int)(wid * 8 + (lane >> 3));
  bool valid = (n < N_NODES);
  if (!valid) n = N_NODES - 1;
  const float ad_n = ad2[n];

  float e0 = as2[n] + ad_n;
  e0 = e0 > 0.f ? e0 : NEG * e0;
  float w0 = __expf(e0);
  float acc = w0 * h2p[(size_t)n*8 + c];   // c==7 slot is 0
  float den = w0;

  const int begin = off[n];
  const int cnt   = off[n+1] - begin;
  for (int base = 0; base < cnt; base += 8) {
    int idx = base + c;
    int sv = (idx < cnt) ? sorted[begin + idx] : 0;
#pragma unroll
    for (int j = 0; j < 8; ++j) {
      if (base + j < cnt) {
        int src = __shfl(sv, j, 8);
        float e = as2[src] + ad_n;
        e = e > 0.f ? e : NEG * e;
        float w = __expf(e);
        acc += w * h2p[(size_t)src*8 + c];
        den += w;
      }
    }
  }
  if (valid) logitsP[(size_t)n*8 + c] = acc / den;
}

// ---------------- final: + b2, log_softmax -> out ---------------------------
__global__ __launch_bounds__(256) void out_kernel(
    const float* __restrict__ logitsP, const void* __restrict__ b2,
    void* __restrict__ out, const int* __restrict__ flag)
{
  const int mode = *flag;
  int n = blockIdx.x * 256 + threadIdx.x;
  if (n >= N_NODES) return;
  float v[C2];
  float m = -1e30f;
#pragma unroll
  for (int c = 0; c < C2; ++c) {
    v[c] = logitsP[(size_t)n*8 + c] + ldmix(b2, c, mode);
    m = fmaxf(m, v[c]);
  }
  float s = 0.f;
#pragma unroll
  for (int c = 0; c < C2; ++c) s += __expf(v[c] - m);
  float lse = m + __logf(s);
  if (mode) {
    float* op = (float*)out;
#pragma unroll
    for (int c = 0; c < C2; ++c) op[(size_t)n*C2 + c] = v[c] - lse;
  } else {
    __hip_bfloat16* op = (__hip_bfloat16*)out;
#pragma unroll
    for (int c = 0; c < C2; ++c) op[(size_t)n*C2 + c] = __float2bfloat16(v[c] - lse);
  }
}

extern "C" void kernel_launch(void* const* d_in, const int* in_sizes, int n_in,
                              void* d_out, int out_size, void* d_ws, size_t ws_size,
                              hipStream_t stream)
{
  const void* x    = d_in[0];
  const int*  ei   = (const int*)d_in[1];
  const void* W1   = d_in[2];
  const void* as1w = d_in[3];
  const void* ad1w = d_in[4];
  const void* b1   = d_in[5];
  const void* W2   = d_in[6];
  const void* as2w = d_in[7];
  const void* ad2w = d_in[8];
  const void* b2   = d_in[9];

  // ---- workspace layout (float units), total 11.45M floats = 45.8 MB ----
  int*   flag = (int*)d_ws;
  float* ws   = (float*)d_ws + 16;

  float*  A      = ws;                      // region A: [0, 3.2M)
  __bf16* h1b    = (__bf16*)A;              // 6.4M bf16 (dead after aggregate1)
  float*  h2p    = A;                       // 0.8M (aliases dead h1b)
  float*  as2    = A + 800000;              // 0.1M
  float*  ad2    = A + 900000;              // 0.1M
  float*  logitsP= A + 1000000;             // 0.8M (ends 1.8M < 3.2M)

  float*  as1    = ws + 3200000;            // [3.2M, 4.0M)
  float*  ad1    = ws + 4000000;            // [4.0M, 4.8M)
  __bf16* out1   = (__bf16*)(ws + 4800000); // [4.8M, 8.0M) : 6.4M bf16
  int*    pairs  = (int*)(ws + 4800000);    // 3.2M ints, aliases out1 (dead
                                            //   until aggregate1 writes it;
                                            //   pairs dead after csrbuild)
  int*    off    = (int*)(ws + 8000000);    // 100001 ints
  int*    bh     = (int*)(ws + 8110000);    // 391 ints (bucket hist)
  int*    bb     = (int*)(ws + 8112000);    // 392 ints (bucket base)
  int*    bcur   = (int*)(ws + 8114000);    // 391 ints (bucket cursor)
  int*    sorted = (int*)(ws + 8250000);    // [8.25M, 11.45M) : 3.2M ints

  detect_kernel<<<1, 64, 0, stream>>>((const unsigned int*)x, flag);
  hipMemsetAsync(bh, 0, NBUCK * sizeof(int), stream);

  gemm1_kernel<<<(N_NODES + G1_ROWS - 1) / G1_ROWS, 256, 0, stream>>>(x, W1, h1b, flag);
  alpha1_kernel<<<(N_NODES * NHEAD + 255) / 256, 256, 0, stream>>>(h1b, as1w, ad1w, as1, ad1, flag);

  // CSR build (two-level binned; dst-major order == CSR order)
  buckhist_kernel<<<(N_EDGES + 4095) / 4096, 256, 0, stream>>>(ei, bh);
  buckscan_kernel<<<1, 512, 0, stream>>>(bh, bb, bcur);
  buckscatter_kernel<<<(N_EDGES + CHB - 1) / CHB, 256, 0, stream>>>(ei, bcur, pairs);
  csrbuild_kernel<<<NBUCK, 256, 0, stream>>>(bb, pairs, off, sorted);

  aggregate1_kernel<<<(N_NODES + 3) / 4, 256, 0, stream>>>(
      off, sorted, h1b, as1, ad1, b1, out1, flag);

  h2_kernel<<<(N_NODES + 255) / 256, 256, 0, stream>>>(out1, W2, as2w, ad2w, h2p, as2, ad2, flag);

  aggregate2_kernel<<<(N_NODES/8 + 3) / 4 + 1, 256, 0, stream>>>(
      off, sorted, h2p, as2, ad2, logitsP);

  out_kernel<<<(N_NODES + 255) / 256, 256, 0, stream>>>(logitsP, b2, d_out, flag);
}

// Round 3
// 795.641 us; speedup vs baseline: 1.1110x; 1.0606x over previous
//
#include <hip/hip_runtime.h>
#include <hip/hip_bf16.h>

#define N_NODES 100000
#define N_EDGES 3200000
#define F_IN 512
#define NHEAD 8
#define CH1 8
#define F1 64   // NHEAD*CH1
#define C2 7
#define NEG 0.2f
#define NBUCK 391   // dst>>8 : 99999>>8 = 390

typedef __bf16 bf16x8 __attribute__((ext_vector_type(8)));
typedef float  f32x4  __attribute__((ext_vector_type(4)));
typedef unsigned int u32x4 __attribute__((ext_vector_type(4)));

union U4BF8 { u32x4 u; bf16x8 v; };

// load element i of a buffer whose dtype is f32 (mode=1) or bf16 (mode=0)
__device__ __forceinline__ float ldmix(const void* p, size_t i, int f32mode) {
  if (f32mode) return ((const float*)p)[i];
  union { unsigned short u; __bf16 b; } c;
  c.u = ((const unsigned short*)p)[i];
  return (float)c.b;
}

// ---------------- dtype detection: 1 wave -----------------------------------
__global__ void detect_kernel(const unsigned int* __restrict__ x, int* __restrict__ flag) {
  int lane = threadIdx.x & 63;
  unsigned int w = x[lane];
  union { unsigned short u; __bf16 b; } c;
  c.u = (unsigned short)(w & 0xFFFFu);
  float v = (float)c.b;
  bool big = !(fabsf(v) <= 1e6f);   // huge or NaN -> f32 data read as bf16
  unsigned long long m = __ballot(big);
  if (lane == 0) *flag = (m != 0ull) ? 1 : 0;
}

// ---------------- GEMM: h1[N,64] = x[N,512] @ W1[512,64]  (bf16 out) -------
// v3: 16KB chunks (64 rows x 256B), 32KB LDS/block -> 4 blocks/CU
// (launch_bounds(256,4)); round-2's 64KB/block capped us at 2 blocks/CU and
// per-CU in-flight bytes ~1KB (Little's law @ 537 GB/s). 2-deep prefetch
// prologue; f32: 8 chunks x 2 k-steps, bf16: 4 chunks x 4 k-steps.
#define G1_ROWS 64
#define G1_CHUNK 256   // bytes per row per chunk

__device__ __forceinline__ int g1_swz16(int g, int row) {
  return (g & 8) | ((g ^ row) & 7);
}

// stage one 16KB chunk: 16 granule-blocks of 1KB; LDS dest linear,
// global source pre-swizzled so lds[row][g'] = x[row][swz(g',row)].
__device__ __forceinline__ void g1_stage(const char* xb, char* ldsbuf, int rowBase,
                                         int cByte, int wl, int lane, int rowBytes)
{
#pragma unroll
  for (int i = 0; i < 4; ++i) {
    int G   = ((i * 4 + wl) << 6) + lane;   // granule id in [0,1024)
    int row = G >> 4;                       // 16 granules (256B) per row
    int gp  = G & 15;
    int g   = g1_swz16(gp, row);
    int grow = rowBase + row; if (grow > N_NODES - 1) grow = N_NODES - 1;
    const char* src = xb + (size_t)grow * rowBytes + cByte + g * 16;
    __builtin_amdgcn_global_load_lds(
        (const __attribute__((address_space(1))) void*)src,
        (__attribute__((address_space(3))) void*)(ldsbuf + ((i * 4 + wl) << 10)),
        16, 0, 0);
  }
}

// compute chunk C (f32 data in LDS): 4 row-tiles x 2 k-steps
__device__ __forceinline__ void g1_comp_f32(const char* ldsbuf, const bf16x8* bfrag,
                                            f32x4* acc, int C, int m, int q)
{
#pragma unroll
  for (int rt = 0; rt < 4; ++rt) {
    const int row = rt * 16 + m;
    const char* rbase = ldsbuf + row * 256;
#pragma unroll
    for (int ks = 0; ks < 2; ++ks) {
      int g0 = ks * 8 + q * 2;
      int s0 = g1_swz16(g0, row);
      int s1 = g1_swz16(g0 + 1, row);
      f32x4 lo = *(const f32x4*)(rbase + s0 * 16);
      f32x4 hi = *(const f32x4*)(rbase + s1 * 16);
      bf16x8 av;
#pragma unroll
      for (int j = 0; j < 4; ++j) { av[j] = (__bf16)lo[j]; av[4 + j] = (__bf16)hi[j]; }
      acc[rt] = __builtin_amdgcn_mfma_f32_16x16x32_bf16(av, bfrag[C * 2 + ks], acc[rt], 0, 0, 0);
    }
  }
}

// compute chunk C (bf16 data in LDS): 4 row-tiles x 4 k-steps
__device__ __forceinline__ void g1_comp_bf16(const char* ldsbuf, const bf16x8* bfrag,
                                             f32x4* acc, int C, int m, int q)
{
#pragma unroll
  for (int rt = 0; rt < 4; ++rt) {
    const int row = rt * 16 + m;
    const char* rbase = ldsbuf + row * 256;
#pragma unroll
    for (int ks = 0; ks < 4; ++ks) {
      int g0 = ks * 4 + q;
      int s0 = g1_swz16(g0, row);
      U4BF8 a;
      a.u = *(const u32x4*)(rbase + s0 * 16);
      acc[rt] = __builtin_amdgcn_mfma_f32_16x16x32_bf16(a.v, bfrag[C * 4 + ks], acc[rt], 0, 0, 0);
    }
  }
}

__global__ __launch_bounds__(256, 4) void gemm1_kernel(
    const void* __restrict__ x, const void* __restrict__ W1,
    __bf16* __restrict__ h1, const int* __restrict__ flag)
{
  __shared__ __align__(128) char lds[2][16384];
  const int mode = *flag;
  const int lane = threadIdx.x & 63;
  const int wl   = threadIdx.x >> 6;
  const int c0   = wl * 16;
  const int m    = lane & 15;
  const int q    = lane >> 4;

  const int rowBase = blockIdx.x * G1_ROWS;
  const char* xb = (const char*)x;
  const int RB = mode ? 2048 : 1024;

  // 2-deep prefetch before the (scattered) W1 fragment loads
  g1_stage(xb, lds[0], rowBase, 0,        wl, lane, RB);
  g1_stage(xb, lds[1], rowBase, G1_CHUNK, wl, lane, RB);

  bf16x8 bfrag[16];
#pragma unroll
  for (int t = 0; t < 16; ++t) {
    bf16x8 tv;
#pragma unroll
    for (int j = 0; j < 8; ++j)
      tv[j] = (__bf16)ldmix(W1, (size_t)(32 * t + q * 8 + j) * F1 + c0 + m, mode);
    bfrag[t] = tv;
  }

  f32x4 acc[4];
#pragma unroll
  for (int rt = 0; rt < 4; ++rt) acc[rt] = (f32x4){0.f, 0.f, 0.f, 0.f};

  __syncthreads();
  if (mode) {
#pragma unroll
    for (int c = 0; c < 8; ++c) {
      g1_comp_f32(lds[c & 1], bfrag, acc, c, m, q);
      __syncthreads();
      if (c + 2 < 8) g1_stage(xb, lds[c & 1], rowBase, (c + 2) * G1_CHUNK, wl, lane, RB);
    }
  } else {
#pragma unroll
    for (int c = 0; c < 4; ++c) {
      g1_comp_bf16(lds[c & 1], bfrag, acc, c, m, q);
      __syncthreads();
      if (c + 2 < 4) g1_stage(xb, lds[c & 1], rowBase, (c + 2) * G1_CHUNK, wl, lane, RB);
    }
  }

#pragma unroll
  for (int rt = 0; rt < 4; ++rt) {
#pragma unroll
    for (int j = 0; j < 4; ++j) {
      int row = rowBase + rt * 16 + q * 4 + j;
      if (row < N_NODES) h1[(size_t)row * F1 + c0 + m] = (__bf16)acc[rt][j];
    }
  }
}

// ---------------- alpha_s1/alpha_d1 [N,8] ----------------------------------
__global__ __launch_bounds__(256) void alpha1_kernel(
    const __bf16* __restrict__ h1,
    const void* __restrict__ a_src, const void* __restrict__ a_dst,
    float* __restrict__ as, float* __restrict__ ad, const int* __restrict__ flag)
{
  const int mode = *flag;
  int i = blockIdx.x * 256 + threadIdx.x;   // n*8+h
  if (i >= N_NODES * NHEAD) return;
  int h = i & 7;
  const __bf16* hp = h1 + (size_t)(i >> 3) * F1 + h * CH1;
  U4BF8 a; a.u = *(const u32x4*)hp;         // 8 bf16 in one 16B load
  float s = 0.f, d = 0.f;
#pragma unroll
  for (int c = 0; c < CH1; ++c) {
    float hv = (float)a.v[c];
    s += hv * ldmix(a_src, h*CH1 + c, mode);
    d += hv * ldmix(a_dst, h*CH1 + c, mode);
  }
  as[i] = s; ad[i] = d;
}

// ---------------- CSR build, two-level binned -------------------------------
// Phase A: bucket histogram (LDS-aggregated)
__global__ __launch_bounds__(256) void buckhist_kernel(
    const int* __restrict__ ei, int* __restrict__ bh)
{
  __shared__ int h[NBUCK];
  for (int i = threadIdx.x; i < NBUCK; i += 256) h[i] = 0;
  __syncthreads();
  int start = blockIdx.x * 4096;
  for (int i = threadIdx.x; i < 4096; i += 256) {
    int e = start + i;
    if (e < N_EDGES) atomicAdd(&h[ei[N_EDGES + e] >> 8], 1);
  }
  __syncthreads();
  for (int i = threadIdx.x; i < NBUCK; i += 256) {
    int c = h[i];
    if (c) atomicAdd(&bh[i], c);
  }
}

// Phase B-scan: exclusive scan of 391 bucket counts -> bases + cursors
__global__ __launch_bounds__(512) void buckscan_kernel(
    const int* __restrict__ bh, int* __restrict__ bb, int* __restrict__ bcur)
{
  __shared__ int s[512];
  int t = threadIdx.x;
  int v = (t < NBUCK) ? bh[t] : 0;
  s[t] = v;
  __syncthreads();
#pragma unroll
  for (int o = 1; o < 512; o <<= 1) {
    int u = (t >= o) ? s[t - o] : 0;
    __syncthreads();
    s[t] += u;
    __syncthreads();
  }
  if (t < NBUCK) { bb[t] = s[t] - v; bcur[t] = s[t] - v; }
  if (t == NBUCK - 1) bb[NBUCK] = s[t];
}

// Phase B: scatter packed (src<<8 | dst&255) into bucket-ordered `pairs`.
// Per-block LDS histogram -> one global range-claim per bucket -> dense writes.
#define CHB 16384
__global__ __launch_bounds__(256) void buckscatter_kernel(
    const int* __restrict__ ei, int* __restrict__ bcur, int* __restrict__ pairs)
{
  __shared__ int h[NBUCK];
  __shared__ int base[NBUCK];
  for (int i = threadIdx.x; i < NBUCK; i += 256) h[i] = 0;
  __syncthreads();
  int start = blockIdx.x * CHB;
  for (int i = threadIdx.x; i < CHB; i += 256) {
    int e = start + i;
    if (e < N_EDGES) atomicAdd(&h[ei[N_EDGES + e] >> 8], 1);
  }
  __syncthreads();
  for (int i = threadIdx.x; i < NBUCK; i += 256) {
    int c = h[i];
    base[i] = c ? atomicAdd(&bcur[i], c) : 0;
    h[i] = 0;
  }
  __syncthreads();
  for (int i = threadIdx.x; i < CHB; i += 256) {
    int e = start + i;
    if (e < N_EDGES) {
      int dst = ei[N_EDGES + e];
      int src = ei[e];
      int b = dst >> 8;
      int pos = base[b] + atomicAdd(&h[b], 1);
      pairs[pos] = (src << 8) | (dst & 255);
    }
  }
}

// Phase C: one block per bucket: LDS per-dst hist + scan -> off[] AND sorted[]
__global__ __launch_bounds__(256) void csrbuild_kernel(
    const int* __restrict__ bb, const int* __restrict__ pairs,
    int* __restrict__ off, int* __restrict__ sorted)
{
  __shared__ int cnt[256];
  __shared__ int scan[256];
  int b = blockIdx.x;
  int lo = bb[b], hi = bb[b+1];
  int t = threadIdx.x;
  cnt[t] = 0;
  __syncthreads();
  for (int i = lo + t; i < hi; i += 256)
    atomicAdd(&cnt[pairs[i] & 255], 1);
  __syncthreads();
  int v = cnt[t];
  scan[t] = v;
  __syncthreads();
#pragma unroll
  for (int o = 1; o < 256; o <<= 1) {
    int u = (t >= o) ? scan[t - o] : 0;
    __syncthreads();
    scan[t] += u;
    __syncthreads();
  }
  int excl = scan[t] - v;
  int node = b * 256 + t;
  if (node < N_NODES) off[node] = lo + excl;
  if (b == 0 && t == 0) off[N_NODES] = N_EDGES;
  __syncthreads();
  cnt[t] = excl;   // cursor
  __syncthreads();
  for (int i = lo + t; i < hi; i += 256) {
    int p = pairs[i];
    int w = lo + atomicAdd(&cnt[p & 255], 1);
    sorted[w] = p >> 8;
  }
}

// ---------------- layer-1 aggregate: one wave per dst (gather, no atomics) --
// v3: edge loop unrolled by 8 with arithmetic masking -> 8 independent
// gathers in flight (was 1 dependent latency per edge). Invalid lanes hold
// sv=0 so unconditional loads are safe; masked w=0 keeps FP order identical.
__global__ __launch_bounds__(256) void aggregate1_kernel(
    const int* __restrict__ off, const int* __restrict__ sorted,
    const __bf16* __restrict__ h1,
    const float* __restrict__ as, const float* __restrict__ ad,
    const void* __restrict__ b1, __bf16* __restrict__ out1,
    const int* __restrict__ flag)
{
  const int mode = *flag;
  const int lane = threadIdx.x & 63;
  int n = blockIdx.x * 4 + (threadIdx.x >> 6);
  if (n >= N_NODES) return;
  const int h = lane >> 3;
  const float ad_h = ad[n*NHEAD + h];

  // self-loop
  float e0 = as[n*NHEAD + h] + ad_h;
  e0 = e0 > 0.f ? e0 : NEG * e0;
  float w0 = __expf(e0);
  float acc = w0 * (float)h1[(size_t)n*F1 + lane];
  float den = w0;

  const int begin = off[n];
  const int cnt   = off[n+1] - begin;
  for (int base = 0; base < cnt; base += 64) {
    int idx = base + lane;
    int sv = (idx < cnt) ? sorted[begin + idx] : 0;
    int jmax = cnt - base; if (jmax > 64) jmax = 64;
    for (int sub = 0; sub < jmax; sub += 8) {
#pragma unroll
      for (int jj = 0; jj < 8; ++jj) {
        int j = sub + jj;
        int src = __shfl(sv, j & 63);
        float e = as[src*NHEAD + h] + ad_h;
        e = e > 0.f ? e : NEG * e;
        float hv = (float)h1[(size_t)src*F1 + lane];
        float w = (j < jmax) ? __expf(e) : 0.f;
        acc += w * hv;
        den += w;
      }
    }
  }
  out1[(size_t)n*F1 + lane] = (__bf16)(acc / den + ldmix(b1, lane, mode));
}

// ---------------- h2 = out1 @ W2 (padded to 8), alpha2 ----------------------
__global__ __launch_bounds__(256) void h2_kernel(
    const __bf16* __restrict__ out1, const void* __restrict__ W2,
    const void* __restrict__ a_src2, const void* __restrict__ a_dst2,
    float* __restrict__ h2p, float* __restrict__ as2, float* __restrict__ ad2,
    const int* __restrict__ flag)
{
  const int mode = *flag;
  __shared__ float W2f[F1*C2];
  __shared__ float asw[C2], adw[C2];
  int t = threadIdx.x;
  for (int i = t; i < F1*C2; i += 256) W2f[i] = ldmix(W2, i, mode);
  if (t < C2) { asw[t] = ldmix(a_src2, t, mode); adw[t] = ldmix(a_dst2, t, mode); }
  __syncthreads();
  int n = blockIdx.x * 256 + t;
  if (n >= N_NODES) return;
  float r[F1];
  const u32x4* rp = (const u32x4*)(out1 + (size_t)n * F1);   // 8 x 16B loads
#pragma unroll
  for (int k = 0; k < 8; ++k) {
    U4BF8 tv; tv.u = rp[k];
#pragma unroll
    for (int j = 0; j < 8; ++j) r[k*8 + j] = (float)tv.v[j];
  }
  float s = 0.f, d = 0.f;
#pragma unroll
  for (int c = 0; c < C2; ++c) {
    float acc = 0.f;
#pragma unroll
    for (int j = 0; j < F1; ++j) acc += r[j] * W2f[j*C2 + c];
    h2p[(size_t)n*8 + c] = acc;
    s += acc * asw[c]; d += acc * adw[c];
  }
  h2p[(size_t)n*8 + 7] = 0.f;
  as2[n] = s; ad2[n] = d;
}

// ---------------- layer-2 aggregate: 8 dsts per wave, 8 lanes each ----------
__global__ __launch_bounds__(256) void aggregate2_kernel(
    const int* __restrict__ off, const int* __restrict__ sorted,
    const float* __restrict__ h2p,
    const float* __restrict__ as2, const float* __restrict__ ad2,
    float* __restrict__ logitsP)
{
  const int lane = threadIdx.x & 63;
  const int c    = lane & 7;
  long long wid  = (long long)blockIdx.x * 4 + (threadIdx.x >> 6);
  int n = (int)(wid * 8 + (lane >> 3));
  bool valid = (n < N_NODES);
  if (!valid) n = N_NODES - 1;
  const float ad_n = ad2[n];

  float e0 = as2[n] + ad_n;
  e0 = e0 > 0.f ? e0 : NEG * e0;
  float w0 = __expf(e0);
  float acc = w0 * h2p[(size_t)n*8 + c];   // c==7 slot is 0
  float den = w0;

  const int begin = off[n];
  const int cnt   = off[n+1] - begin;
  for (int base = 0; base < cnt; base += 8) {
    int idx = base + c;
    int sv = (idx < cnt) ? sorted[begin + idx] : 0;
#pragma unroll
    for (int j = 0; j < 8; ++j) {
      int src = __shfl(sv, j, 8);
      float e = as2[src] + ad_n;
      e = e > 0.f ? e : NEG * e;
      float hv = h2p[(size_t)src*8 + c];
      float w = (base + j < cnt) ? __expf(e) : 0.f;
      acc += w * hv;
      den += w;
    }
  }
  if (valid) logitsP[(size_t)n*8 + c] = acc / den;
}

// ---------------- final: + b2, log_softmax -> out ---------------------------
__global__ __launch_bounds__(256) void out_kernel(
    const float* __restrict__ logitsP, const void* __restrict__ b2,
    void* __restrict__ out, const int* __restrict__ flag)
{
  const int mode = *flag;
  int n = blockIdx.x * 256 + threadIdx.x;
  if (n >= N_NODES) return;
  float v[C2];
  float m = -1e30f;
#pragma unroll
  for (int c = 0; c < C2; ++c) {
    v[c] = logitsP[(size_t)n*8 + c] + ldmix(b2, c, mode);
    m = fmaxf(m, v[c]);
  }
  float s = 0.f;
#pragma unroll
  for (int c = 0; c < C2; ++c) s += __expf(v[c] - m);
  float lse = m + __logf(s);
  if (mode) {
    float* op = (float*)out;
#pragma unroll
    for (int c = 0; c < C2; ++c) op[(size_t)n*C2 + c] = v[c] - lse;
  } else {
    __hip_bfloat16* op = (__hip_bfloat16*)out;
#pragma unroll
    for (int c = 0; c < C2; ++c) op[(size_t)n*C2 + c] = __float2bfloat16(v[c] - lse);
  }
}

extern "C" void kernel_launch(void* const* d_in, const int* in_sizes, int n_in,
                              void* d_out, int out_size, void* d_ws, size_t ws_size,
                              hipStream_t stream)
{
  const void* x    = d_in[0];
  const int*  ei   = (const int*)d_in[1];
  const void* W1   = d_in[2];
  const void* as1w = d_in[3];
  const void* ad1w = d_in[4];
  const void* b1   = d_in[5];
  const void* W2   = d_in[6];
  const void* as2w = d_in[7];
  const void* ad2w = d_in[8];
  const void* b2   = d_in[9];

  // ---- workspace layout (float units), total 11.45M floats = 45.8 MB ----
  int*   flag = (int*)d_ws;
  float* ws   = (float*)d_ws + 16;

  float*  A      = ws;                      // region A: [0, 3.2M)
  __bf16* h1b    = (__bf16*)A;              // 6.4M bf16 (dead after aggregate1)
  float*  h2p    = A;                       // 0.8M (aliases dead h1b)
  float*  as2    = A + 800000;              // 0.1M
  float*  ad2    = A + 900000;              // 0.1M
  float*  logitsP= A + 1000000;             // 0.8M (ends 1.8M < 3.2M)

  float*  as1    = ws + 3200000;            // [3.2M, 4.0M)
  float*  ad1    = ws + 4000000;            // [4.0M, 4.8M)
  __bf16* out1   = (__bf16*)(ws + 4800000); // [4.8M, 8.0M) : 6.4M bf16
  int*    pairs  = (int*)(ws + 4800000);    // 3.2M ints, aliases out1 (dead
                                            //   until aggregate1 writes it;
                                            //   pairs dead after csrbuild)
  int*    off    = (int*)(ws + 8000000);    // 100001 ints
  int*    bh     = (int*)(ws + 8110000);    // 391 ints (bucket hist)
  int*    bb     = (int*)(ws + 8112000);    // 392 ints (bucket base)
  int*    bcur   = (int*)(ws + 8114000);    // 391 ints (bucket cursor)
  int*    sorted = (int*)(ws + 8250000);    // [8.25M, 11.45M) : 3.2M ints

  detect_kernel<<<1, 64, 0, stream>>>((const unsigned int*)x, flag);
  hipMemsetAsync(bh, 0, NBUCK * sizeof(int), stream);

  gemm1_kernel<<<(N_NODES + G1_ROWS - 1) / G1_ROWS, 256, 0, stream>>>(x, W1, h1b, flag);
  alpha1_kernel<<<(N_NODES * NHEAD + 255) / 256, 256, 0, stream>>>(h1b, as1w, ad1w, as1, ad1, flag);

  // CSR build (two-level binned; dst-major order == CSR order)
  buckhist_kernel<<<(N_EDGES + 4095) / 4096, 256, 0, stream>>>(ei, bh);
  buckscan_kernel<<<1, 512, 0, stream>>>(bh, bb, bcur);
  buckscatter_kernel<<<(N_EDGES + CHB - 1) / CHB, 256, 0, stream>>>(ei, bcur, pairs);
  csrbuild_kernel<<<NBUCK, 256, 0, stream>>>(bb, pairs, off, sorted);

  aggregate1_kernel<<<(N_NODES + 3) / 4, 256, 0, stream>>>(
      off, sorted, h1b, as1, ad1, b1, out1, flag);

  h2_kernel<<<(N_NODES + 255) / 256, 256, 0, stream>>>(out1, W2, as2w, ad2w, h2p, as2, ad2, flag);

  aggregate2_kernel<<<(N_NODES/8 + 3) / 4 + 1, 256, 0, stream>>>(
      off, sorted, h2p, as2, ad2, logitsP);

  out_kernel<<<(N_NODES + 255) / 256, 256, 0, stream>>>(logitsP, b2, d_out, flag);
}

// Round 4
// 714.327 us; speedup vs baseline: 1.2375x; 1.1138x over previous
//
#include <hip/hip_runtime.h>
#include <hip/hip_bf16.h>

#define N_NODES 100000
#define N_EDGES 3200000
#define F_IN 512
#define NHEAD 8
#define CH1 8
#define F1 64   // NHEAD*CH1
#define C2 7
#define NEG 0.2f
#define NBUCK 391   // dst>>8 : 99999>>8 = 390

typedef __bf16 bf16x8 __attribute__((ext_vector_type(8)));
typedef float  f32x4  __attribute__((ext_vector_type(4)));
typedef unsigned int u32x4 __attribute__((ext_vector_type(4)));

union U4BF8 { u32x4 u; bf16x8 v; };

// load element i of a buffer whose dtype is f32 (mode=1) or bf16 (mode=0)
__device__ __forceinline__ float ldmix(const void* p, size_t i, int f32mode) {
  if (f32mode) return ((const float*)p)[i];
  union { unsigned short u; __bf16 b; } c;
  c.u = ((const unsigned short*)p)[i];
  return (float)c.b;
}

// ---------------- dtype detection: 1 wave -----------------------------------
__global__ void detect_kernel(const unsigned int* __restrict__ x, int* __restrict__ flag) {
  int lane = threadIdx.x & 63;
  unsigned int w = x[lane];
  union { unsigned short u; __bf16 b; } c;
  c.u = (unsigned short)(w & 0xFFFFu);
  float v = (float)c.b;
  bool big = !(fabsf(v) <= 1e6f);   // huge or NaN -> f32 data read as bf16
  unsigned long long m = __ballot(big);
  if (lane == 0) *flag = (m != 0ull) ? 1 : 0;
}

// ---------------- GEMM: h1[N,64] = x[N,512] @ W1[512,64]  (bf16 out) -------
// v3: 16KB chunks (64 rows x 256B), 32KB LDS/block -> 4 blocks/CU
// (launch_bounds(256,4)); 2-deep prefetch prologue.
#define G1_ROWS 64
#define G1_CHUNK 256   // bytes per row per chunk

__device__ __forceinline__ int g1_swz16(int g, int row) {
  return (g & 8) | ((g ^ row) & 7);
}

// stage one 16KB chunk: LDS dest linear, global source pre-swizzled so
// lds[row][g'] = x[row][swz(g',row)].
__device__ __forceinline__ void g1_stage(const char* xb, char* ldsbuf, int rowBase,
                                         int cByte, int wl, int lane, int rowBytes)
{
#pragma unroll
  for (int i = 0; i < 4; ++i) {
    int G   = ((i * 4 + wl) << 6) + lane;   // granule id in [0,1024)
    int row = G >> 4;                       // 16 granules (256B) per row
    int gp  = G & 15;
    int g   = g1_swz16(gp, row);
    int grow = rowBase + row; if (grow > N_NODES - 1) grow = N_NODES - 1;
    const char* src = xb + (size_t)grow * rowBytes + cByte + g * 16;
    __builtin_amdgcn_global_load_lds(
        (const __attribute__((address_space(1))) void*)src,
        (__attribute__((address_space(3))) void*)(ldsbuf + ((i * 4 + wl) << 10)),
        16, 0, 0);
  }
}

// compute chunk C (f32 data in LDS): 4 row-tiles x 2 k-steps
__device__ __forceinline__ void g1_comp_f32(const char* ldsbuf, const bf16x8* bfrag,
                                            f32x4* acc, int C, int m, int q)
{
#pragma unroll
  for (int rt = 0; rt < 4; ++rt) {
    const int row = rt * 16 + m;
    const char* rbase = ldsbuf + row * 256;
#pragma unroll
    for (int ks = 0; ks < 2; ++ks) {
      int g0 = ks * 8 + q * 2;
      int s0 = g1_swz16(g0, row);
      int s1 = g1_swz16(g0 + 1, row);
      f32x4 lo = *(const f32x4*)(rbase + s0 * 16);
      f32x4 hi = *(const f32x4*)(rbase + s1 * 16);
      bf16x8 av;
#pragma unroll
      for (int j = 0; j < 4; ++j) { av[j] = (__bf16)lo[j]; av[4 + j] = (__bf16)hi[j]; }
      acc[rt] = __builtin_amdgcn_mfma_f32_16x16x32_bf16(av, bfrag[C * 2 + ks], acc[rt], 0, 0, 0);
    }
  }
}

// compute chunk C (bf16 data in LDS): 4 row-tiles x 4 k-steps
__device__ __forceinline__ void g1_comp_bf16(const char* ldsbuf, const bf16x8* bfrag,
                                             f32x4* acc, int C, int m, int q)
{
#pragma unroll
  for (int rt = 0; rt < 4; ++rt) {
    const int row = rt * 16 + m;
    const char* rbase = ldsbuf + row * 256;
#pragma unroll
    for (int ks = 0; ks < 4; ++ks) {
      int g0 = ks * 4 + q;
      int s0 = g1_swz16(g0, row);
      U4BF8 a;
      a.u = *(const u32x4*)(rbase + s0 * 16);
      acc[rt] = __builtin_amdgcn_mfma_f32_16x16x32_bf16(a.v, bfrag[C * 4 + ks], acc[rt], 0, 0, 0);
    }
  }
}

__global__ __launch_bounds__(256, 4) void gemm1_kernel(
    const void* __restrict__ x, const void* __restrict__ W1,
    __bf16* __restrict__ h1, const int* __restrict__ flag)
{
  __shared__ __align__(128) char lds[2][16384];
  const int mode = *flag;
  const int lane = threadIdx.x & 63;
  const int wl   = threadIdx.x >> 6;
  const int c0   = wl * 16;
  const int m    = lane & 15;
  const int q    = lane >> 4;

  const int rowBase = blockIdx.x * G1_ROWS;
  const char* xb = (const char*)x;
  const int RB = mode ? 2048 : 1024;

  // 2-deep prefetch before the (scattered) W1 fragment loads
  g1_stage(xb, lds[0], rowBase, 0,        wl, lane, RB);
  g1_stage(xb, lds[1], rowBase, G1_CHUNK, wl, lane, RB);

  bf16x8 bfrag[16];
#pragma unroll
  for (int t = 0; t < 16; ++t) {
    bf16x8 tv;
#pragma unroll
    for (int j = 0; j < 8; ++j)
      tv[j] = (__bf16)ldmix(W1, (size_t)(32 * t + q * 8 + j) * F1 + c0 + m, mode);
    bfrag[t] = tv;
  }

  f32x4 acc[4];
#pragma unroll
  for (int rt = 0; rt < 4; ++rt) acc[rt] = (f32x4){0.f, 0.f, 0.f, 0.f};

  __syncthreads();
  if (mode) {
#pragma unroll
    for (int c = 0; c < 8; ++c) {
      g1_comp_f32(lds[c & 1], bfrag, acc, c, m, q);
      __syncthreads();
      if (c + 2 < 8) g1_stage(xb, lds[c & 1], rowBase, (c + 2) * G1_CHUNK, wl, lane, RB);
    }
  } else {
#pragma unroll
    for (int c = 0; c < 4; ++c) {
      g1_comp_bf16(lds[c & 1], bfrag, acc, c, m, q);
      __syncthreads();
      if (c + 2 < 4) g1_stage(xb, lds[c & 1], rowBase, (c + 2) * G1_CHUNK, wl, lane, RB);
    }
  }

#pragma unroll
  for (int rt = 0; rt < 4; ++rt) {
#pragma unroll
    for (int j = 0; j < 4; ++j) {
      int row = rowBase + rt * 16 + q * 4 + j;
      if (row < N_NODES) h1[(size_t)row * F1 + c0 + m] = (__bf16)acc[rt][j];
    }
  }
}

// ---------------- alpha_s1/alpha_d1 [N,8] ----------------------------------
__global__ __launch_bounds__(256) void alpha1_kernel(
    const __bf16* __restrict__ h1,
    const void* __restrict__ a_src, const void* __restrict__ a_dst,
    float* __restrict__ as, float* __restrict__ ad, const int* __restrict__ flag)
{
  const int mode = *flag;
  int i = blockIdx.x * 256 + threadIdx.x;   // n*8+h
  if (i >= N_NODES * NHEAD) return;
  int h = i & 7;
  const __bf16* hp = h1 + (size_t)(i >> 3) * F1 + h * CH1;
  U4BF8 a; a.u = *(const u32x4*)hp;         // 8 bf16 in one 16B load
  float s = 0.f, d = 0.f;
#pragma unroll
  for (int c = 0; c < CH1; ++c) {
    float hv = (float)a.v[c];
    s += hv * ldmix(a_src, h*CH1 + c, mode);
    d += hv * ldmix(a_dst, h*CH1 + c, mode);
  }
  as[i] = s; ad[i] = d;
}

// ---------------- CSR build, two-level binned -------------------------------
// Phase A: bucket histogram (LDS-aggregated)
__global__ __launch_bounds__(256) void buckhist_kernel(
    const int* __restrict__ ei, int* __restrict__ bh)
{
  __shared__ int h[NBUCK];
  for (int i = threadIdx.x; i < NBUCK; i += 256) h[i] = 0;
  __syncthreads();
  int start = blockIdx.x * 4096;
  for (int i = threadIdx.x; i < 4096; i += 256) {
    int e = start + i;
    if (e < N_EDGES) atomicAdd(&h[ei[N_EDGES + e] >> 8], 1);
  }
  __syncthreads();
  for (int i = threadIdx.x; i < NBUCK; i += 256) {
    int c = h[i];
    if (c) atomicAdd(&bh[i], c);
  }
}

// Phase B-scan: exclusive scan of 391 bucket counts -> bases + cursors
__global__ __launch_bounds__(512) void buckscan_kernel(
    const int* __restrict__ bh, int* __restrict__ bb, int* __restrict__ bcur)
{
  __shared__ int s[512];
  int t = threadIdx.x;
  int v = (t < NBUCK) ? bh[t] : 0;
  s[t] = v;
  __syncthreads();
#pragma unroll
  for (int o = 1; o < 512; o <<= 1) {
    int u = (t >= o) ? s[t - o] : 0;
    __syncthreads();
    s[t] += u;
    __syncthreads();
  }
  if (t < NBUCK) { bb[t] = s[t] - v; bcur[t] = s[t] - v; }
  if (t == NBUCK - 1) bb[NBUCK] = s[t];
}

// Phase B: scatter packed (src<<8 | dst&255) into bucket-ordered `pairs`.
// Per-block LDS histogram -> one global range-claim per bucket -> dense writes.
#define CHB 16384
__global__ __launch_bounds__(256) void buckscatter_kernel(
    const int* __restrict__ ei, int* __restrict__ bcur, int* __restrict__ pairs)
{
  __shared__ int h[NBUCK];
  __shared__ int base[NBUCK];
  for (int i = threadIdx.x; i < NBUCK; i += 256) h[i] = 0;
  __syncthreads();
  int start = blockIdx.x * CHB;
  for (int i = threadIdx.x; i < CHB; i += 256) {
    int e = start + i;
    if (e < N_EDGES) atomicAdd(&h[ei[N_EDGES + e] >> 8], 1);
  }
  __syncthreads();
  for (int i = threadIdx.x; i < NBUCK; i += 256) {
    int c = h[i];
    base[i] = c ? atomicAdd(&bcur[i], c) : 0;
    h[i] = 0;
  }
  __syncthreads();
  for (int i = threadIdx.x; i < CHB; i += 256) {
    int e = start + i;
    if (e < N_EDGES) {
      int dst = ei[N_EDGES + e];
      int src = ei[e];
      int b = dst >> 8;
      int pos = base[b] + atomicAdd(&h[b], 1);
      pairs[pos] = (src << 8) | (dst & 255);
    }
  }
}

// Phase C: one block per bucket: LDS per-dst hist + scan -> off[] AND sorted[]
__global__ __launch_bounds__(256) void csrbuild_kernel(
    const int* __restrict__ bb, const int* __restrict__ pairs,
    int* __restrict__ off, int* __restrict__ sorted)
{
  __shared__ int cnt[256];
  __shared__ int scan[256];
  int b = blockIdx.x;
  int lo = bb[b], hi = bb[b+1];
  int t = threadIdx.x;
  cnt[t] = 0;
  __syncthreads();
  for (int i = lo + t; i < hi; i += 256)
    atomicAdd(&cnt[pairs[i] & 255], 1);
  __syncthreads();
  int v = cnt[t];
  scan[t] = v;
  __syncthreads();
#pragma unroll
  for (int o = 1; o < 256; o <<= 1) {
    int u = (t >= o) ? scan[t - o] : 0;
    __syncthreads();
    scan[t] += u;
    __syncthreads();
  }
  int excl = scan[t] - v;
  int node = b * 256 + t;
  if (node < N_NODES) off[node] = lo + excl;
  if (b == 0 && t == 0) off[N_NODES] = N_EDGES;
  __syncthreads();
  cnt[t] = excl;   // cursor
  __syncthreads();
  for (int i = lo + t; i < hi; i += 256) {
    int p = pairs[i];
    int w = lo + atomicAdd(&cnt[p & 255], 1);
    sorted[w] = p >> 8;
  }
}

// ---------------- layer-1 aggregate: one wave per dst (gather, no atomics) --
// v4: per 64-edge block, lane j computes ALL 8 heads' w for ITS edge
// (2 f32x4 as-loads + 8 exp instrs per block, vs 64 gathers + 64 exp instrs
// in v3's per-edge form), stages w into a per-wave LDS strip w[64][8], then
// the per-edge loop is: bpermute(src) + ds_read(w[j][h], broadcast) +
// h1 gather + 2 fma. Unroll 16 -> 16 gathers in flight. Same FP order
// (masked lanes contribute exact +0.0) -> bit-identical results.
__global__ __launch_bounds__(256) void aggregate1_kernel(
    const int* __restrict__ off, const int* __restrict__ sorted,
    const __bf16* __restrict__ h1,
    const float* __restrict__ as, const float* __restrict__ ad,
    const void* __restrict__ b1, __bf16* __restrict__ out1,
    const int* __restrict__ flag)
{
  __shared__ float wlds[4][64][8];
  const int mode = *flag;
  const int lane = threadIdx.x & 63;
  const int wl   = threadIdx.x >> 6;
  int n = blockIdx.x * 4 + wl;
  if (n >= N_NODES) return;
  const int h = lane >> 3;
  const float ad_h = ad[n*NHEAD + h];
  // all 8 ad values for this dst (wave-uniform broadcast loads)
  f32x4 adLo = *(const f32x4*)(ad + (size_t)n * 8);
  f32x4 adHi = *(const f32x4*)(ad + (size_t)n * 8 + 4);

  // self-loop
  float e0 = as[n*NHEAD + h] + ad_h;
  e0 = e0 > 0.f ? e0 : NEG * e0;
  float w0 = __expf(e0);
  float acc = w0 * (float)h1[(size_t)n*F1 + lane];
  float den = w0;

  const int begin = off[n];
  const int cnt   = off[n+1] - begin;
  for (int base = 0; base < cnt; base += 64) {
    int idx = base + lane;
    bool vld = idx < cnt;
    int sv = vld ? sorted[begin + idx] : 0;
    // my edge's attention logits, all 8 heads, vectorized
    f32x4 aLo = *(const f32x4*)(as + (size_t)sv * 8);
    f32x4 aHi = *(const f32x4*)(as + (size_t)sv * 8 + 4);
    f32x4 wLo, wHi;
#pragma unroll
    for (int k = 0; k < 4; ++k) {
      float e  = aLo[k] + adLo[k]; e  = e  > 0.f ? e  : NEG * e;
      float e2 = aHi[k] + adHi[k]; e2 = e2 > 0.f ? e2 : NEG * e2;
      wLo[k] = vld ? __expf(e)  : 0.f;
      wHi[k] = vld ? __expf(e2) : 0.f;
    }
    *(f32x4*)&wlds[wl][lane][0] = wLo;
    *(f32x4*)&wlds[wl][lane][4] = wHi;
    // wave-synchronous: compiler inserts lgkmcnt wait before dependent reads

    int jmax = cnt - base; if (jmax > 64) jmax = 64;
    for (int sub = 0; sub < jmax; sub += 16) {
#pragma unroll
      for (int jj = 0; jj < 16; ++jj) {
        int j = sub + jj;
        int src = __shfl(sv, j);
        float w = wlds[wl][j][h];        // 0 for j >= jmax
        float hv = (float)h1[(size_t)src*F1 + lane];
        acc += w * hv;
        den += w;
      }
    }
  }
  out1[(size_t)n*F1 + lane] = (__bf16)(acc / den + ldmix(b1, lane, mode));
}

// ---------------- h2 = out1 @ W2 (padded to 8), alpha2 ----------------------
__global__ __launch_bounds__(256) void h2_kernel(
    const __bf16* __restrict__ out1, const void* __restrict__ W2,
    const void* __restrict__ a_src2, const void* __restrict__ a_dst2,
    float* __restrict__ h2p, float* __restrict__ as2, float* __restrict__ ad2,
    const int* __restrict__ flag)
{
  const int mode = *flag;
  __shared__ float W2f[F1*C2];
  __shared__ float asw[C2], adw[C2];
  int t = threadIdx.x;
  for (int i = t; i < F1*C2; i += 256) W2f[i] = ldmix(W2, i, mode);
  if (t < C2) { asw[t] = ldmix(a_src2, t, mode); adw[t] = ldmix(a_dst2, t, mode); }
  __syncthreads();
  int n = blockIdx.x * 256 + t;
  if (n >= N_NODES) return;
  float r[F1];
  const u32x4* rp = (const u32x4*)(out1 + (size_t)n * F1);   // 8 x 16B loads
#pragma unroll
  for (int k = 0; k < 8; ++k) {
    U4BF8 tv; tv.u = rp[k];
#pragma unroll
    for (int j = 0; j < 8; ++j) r[k*8 + j] = (float)tv.v[j];
  }
  float s = 0.f, d = 0.f;
#pragma unroll
  for (int c = 0; c < C2; ++c) {
    float acc = 0.f;
#pragma unroll
    for (int j = 0; j < F1; ++j) acc += r[j] * W2f[j*C2 + c];
    h2p[(size_t)n*8 + c] = acc;
    s += acc * asw[c]; d += acc * adw[c];
  }
  h2p[(size_t)n*8 + 7] = 0.f;
  as2[n] = s; ad2[n] = d;
}

// ---------------- layer-2 aggregate: 8 dsts per wave, 8 lanes each ----------
__global__ __launch_bounds__(256) void aggregate2_kernel(
    const int* __restrict__ off, const int* __restrict__ sorted,
    const float* __restrict__ h2p,
    const float* __restrict__ as2, const float* __restrict__ ad2,
    float* __restrict__ logitsP)
{
  const int lane = threadIdx.x & 63;
  const int c    = lane & 7;
  long long wid  = (long long)blockIdx.x * 4 + (threadIdx.x >> 6);
  int n = (int)(wid * 8 + (lane >> 3));
  bool valid = (n < N_NODES);
  if (!valid) n = N_NODES - 1;
  const float ad_n = ad2[n];

  float e0 = as2[n] + ad_n;
  e0 = e0 > 0.f ? e0 : NEG * e0;
  float w0 = __expf(e0);
  float acc = w0 * h2p[(size_t)n*8 + c];   // c==7 slot is 0
  float den = w0;

  const int begin = off[n];
  const int cnt   = off[n+1] - begin;
  for (int base = 0; base < cnt; base += 8) {
    int idx = base + c;
    int sv = (idx < cnt) ? sorted[begin + idx] : 0;
#pragma unroll
    for (int j = 0; j < 8; ++j) {
      int src = __shfl(sv, j, 8);
      float e = as2[src] + ad_n;
      e = e > 0.f ? e : NEG * e;
      float hv = h2p[(size_t)src*8 + c];
      float w = (base + j < cnt) ? __expf(e) : 0.f;
      acc += w * hv;
      den += w;
    }
  }
  if (valid) logitsP[(size_t)n*8 + c] = acc / den;
}

// ---------------- final: + b2, log_softmax -> out ---------------------------
__global__ __launch_bounds__(256) void out_kernel(
    const float* __restrict__ logitsP, const void* __restrict__ b2,
    void* __restrict__ out, const int* __restrict__ flag)
{
  const int mode = *flag;
  int n = blockIdx.x * 256 + threadIdx.x;
  if (n >= N_NODES) return;
  float v[C2];
  float m = -1e30f;
#pragma unroll
  for (int c = 0; c < C2; ++c) {
    v[c] = logitsP[(size_t)n*8 + c] + ldmix(b2, c, mode);
    m = fmaxf(m, v[c]);
  }
  float s = 0.f;
#pragma unroll
  for (int c = 0; c < C2; ++c) s += __expf(v[c] - m);
  float lse = m + __logf(s);
  if (mode) {
    float* op = (float*)out;
#pragma unroll
    for (int c = 0; c < C2; ++c) op[(size_t)n*C2 + c] = v[c] - lse;
  } else {
    __hip_bfloat16* op = (__hip_bfloat16*)out;
#pragma unroll
    for (int c = 0; c < C2; ++c) op[(size_t)n*C2 + c] = __float2bfloat16(v[c] - lse);
  }
}

extern "C" void kernel_launch(void* const* d_in, const int* in_sizes, int n_in,
                              void* d_out, int out_size, void* d_ws, size_t ws_size,
                              hipStream_t stream)
{
  const void* x    = d_in[0];
  const int*  ei   = (const int*)d_in[1];
  const void* W1   = d_in[2];
  const void* as1w = d_in[3];
  const void* ad1w = d_in[4];
  const void* b1   = d_in[5];
  const void* W2   = d_in[6];
  const void* as2w = d_in[7];
  const void* ad2w = d_in[8];
  const void* b2   = d_in[9];

  // ---- workspace layout (float units), total 11.45M floats = 45.8 MB ----
  int*   flag = (int*)d_ws;
  float* ws   = (float*)d_ws + 16;

  float*  A      = ws;                      // region A: [0, 3.2M)
  __bf16* h1b    = (__bf16*)A;              // 6.4M bf16 (dead after aggregate1)
  float*  h2p    = A;                       // 0.8M (aliases dead h1b)
  float*  as2    = A + 800000;              // 0.1M
  float*  ad2    = A + 900000;              // 0.1M
  float*  logitsP= A + 1000000;             // 0.8M (ends 1.8M < 3.2M)

  float*  as1    = ws + 3200000;            // [3.2M, 4.0M)
  float*  ad1    = ws + 4000000;            // [4.0M, 4.8M)
  __bf16* out1   = (__bf16*)(ws + 4800000); // [4.8M, 8.0M) : 6.4M bf16
  int*    pairs  = (int*)(ws + 4800000);    // 3.2M ints, aliases out1 (dead
                                            //   until aggregate1 writes it;
                                            //   pairs dead after csrbuild)
  int*    off    = (int*)(ws + 8000000);    // 100001 ints
  int*    bh     = (int*)(ws + 8110000);    // 391 ints (bucket hist)
  int*    bb     = (int*)(ws + 8112000);    // 392 ints (bucket base)
  int*    bcur   = (int*)(ws + 8114000);    // 391 ints (bucket cursor)
  int*    sorted = (int*)(ws + 8250000);    // [8.25M, 11.45M) : 3.2M ints

  detect_kernel<<<1, 64, 0, stream>>>((const unsigned int*)x, flag);
  hipMemsetAsync(bh, 0, NBUCK * sizeof(int), stream);

  gemm1_kernel<<<(N_NODES + G1_ROWS - 1) / G1_ROWS, 256, 0, stream>>>(x, W1, h1b, flag);
  alpha1_kernel<<<(N_NODES * NHEAD + 255) / 256, 256, 0, stream>>>(h1b, as1w, ad1w, as1, ad1, flag);

  // CSR build (two-level binned; dst-major order == CSR order)
  buckhist_kernel<<<(N_EDGES + 4095) / 4096, 256, 0, stream>>>(ei, bh);
  buckscan_kernel<<<1, 512, 0, stream>>>(bh, bb, bcur);
  buckscatter_kernel<<<(N_EDGES + CHB - 1) / CHB, 256, 0, stream>>>(ei, bcur, pairs);
  csrbuild_kernel<<<NBUCK, 256, 0, stream>>>(bb, pairs, off, sorted);

  aggregate1_kernel<<<(N_NODES + 3) / 4, 256, 0, stream>>>(
      off, sorted, h1b, as1, ad1, b1, out1, flag);

  h2_kernel<<<(N_NODES + 255) / 256, 256, 0, stream>>>(out1, W2, as2w, ad2w, h2p, as2, ad2, flag);

  aggregate2_kernel<<<(N_NODES/8 + 3) / 4 + 1, 256, 0, stream>>>(
      off, sorted, h2p, as2, ad2, logitsP);

  out_kernel<<<(N_NODES + 255) / 256, 256, 0, stream>>>(logitsP, b2, d_out, flag);
}

// Round 5
// 637.592 us; speedup vs baseline: 1.3865x; 1.1204x over previous
//
#include <hip/hip_runtime.h>
#include <hip/hip_bf16.h>

#define N_NODES 100000
#define N_EDGES 3200000
#define F_IN 512
#define NHEAD 8
#define CH1 8
#define F1 64   // NHEAD*CH1
#define C2 7
#define NEG 0.2f
#define NBUCK 391   // dst>>8 : 99999>>8 = 390

typedef __bf16 bf16x8 __attribute__((ext_vector_type(8)));
typedef float  f32x4  __attribute__((ext_vector_type(4)));
typedef unsigned int u32x4 __attribute__((ext_vector_type(4)));

union U4BF8 { u32x4 u; bf16x8 v; };

// load element i of a buffer whose dtype is f32 (mode=1) or bf16 (mode=0)
__device__ __forceinline__ float ldmix(const void* p, size_t i, int f32mode) {
  if (f32mode) return ((const float*)p)[i];
  union { unsigned short u; __bf16 b; } c;
  c.u = ((const unsigned short*)p)[i];
  return (float)c.b;
}

// ---------------- dtype detection: 1 wave -----------------------------------
__global__ void detect_kernel(const unsigned int* __restrict__ x, int* __restrict__ flag) {
  int lane = threadIdx.x & 63;
  unsigned int w = x[lane];
  union { unsigned short u; __bf16 b; } c;
  c.u = (unsigned short)(w & 0xFFFFu);
  float v = (float)c.b;
  bool big = !(fabsf(v) <= 1e6f);   // huge or NaN -> f32 data read as bf16
  unsigned long long m = __ballot(big);
  if (lane == 0) *flag = (m != 0ull) ? 1 : 0;
}

// ---------------- W1 fragment pre-pack (one-time, ~3us) ---------------------
// v5: r4 showed gemm1's 128 scattered per-thread W1 scalar loads are the
// serial chain (VGPR-starved -> ~serialized latencies + scratch spill,
// WRITE_SIZE 12.5->42MB). Pack W1 into fragment-ordered bf16 ONCE; gemm1
// then does 16 coalesced 16B loads from a 64KB L2-resident buffer.
// Layout: W1P[((wl*16+t)*64+lane)*8 + j] = bf16(W1[(32t+q*8+j)*64 + wl*16+m])
__global__ __launch_bounds__(256) void w1pack_kernel(
    const void* __restrict__ W1, __bf16* __restrict__ W1P, const int* __restrict__ flag)
{
  const int mode = *flag;
  int i = blockIdx.x * 256 + threadIdx.x;   // [0, 4096)
  int wl = i >> 10; int t = (i >> 6) & 15; int lane = i & 63;
  int m = lane & 15, q = lane >> 4;
  int c0 = wl * 16;
  bf16x8 tv;
#pragma unroll
  for (int j = 0; j < 8; ++j)
    tv[j] = (__bf16)ldmix(W1, (size_t)(32*t + q*8 + j)*F1 + c0 + m, mode);
  *(bf16x8*)(W1P + (size_t)i * 8) = tv;
}

// ---------------- GEMM: h1[N,64] = x[N,512] @ W1[512,64]  (bf16 out) -------
// 16KB chunks (64 rows x 256B), 32KB LDS/block, 4 blocks/CU, 2-deep prefetch.
#define G1_ROWS 64
#define G1_CHUNK 256   // bytes per row per chunk

__device__ __forceinline__ int g1_swz16(int g, int row) {
  return (g & 8) | ((g ^ row) & 7);
}

// stage one 16KB chunk: LDS dest linear, global source pre-swizzled so
// lds[row][g'] = x[row][swz(g',row)].
__device__ __forceinline__ void g1_stage(const char* xb, char* ldsbuf, int rowBase,
                                         int cByte, int wl, int lane, int rowBytes)
{
#pragma unroll
  for (int i = 0; i < 4; ++i) {
    int G   = ((i * 4 + wl) << 6) + lane;   // granule id in [0,1024)
    int row = G >> 4;                       // 16 granules (256B) per row
    int gp  = G & 15;
    int g   = g1_swz16(gp, row);
    int grow = rowBase + row; if (grow > N_NODES - 1) grow = N_NODES - 1;
    const char* src = xb + (size_t)grow * rowBytes + cByte + g * 16;
    __builtin_amdgcn_global_load_lds(
        (const __attribute__((address_space(1))) void*)src,
        (__attribute__((address_space(3))) void*)(ldsbuf + ((i * 4 + wl) << 10)),
        16, 0, 0);
  }
}

// compute chunk C (f32 data in LDS): 4 row-tiles x 2 k-steps
__device__ __forceinline__ void g1_comp_f32(const char* ldsbuf, const bf16x8* bfrag,
                                            f32x4* acc, int C, int m, int q)
{
#pragma unroll
  for (int rt = 0; rt < 4; ++rt) {
    const int row = rt * 16 + m;
    const char* rbase = ldsbuf + row * 256;
#pragma unroll
    for (int ks = 0; ks < 2; ++ks) {
      int g0 = ks * 8 + q * 2;
      int s0 = g1_swz16(g0, row);
      int s1 = g1_swz16(g0 + 1, row);
      f32x4 lo = *(const f32x4*)(rbase + s0 * 16);
      f32x4 hi = *(const f32x4*)(rbase + s1 * 16);
      bf16x8 av;
#pragma unroll
      for (int j = 0; j < 4; ++j) { av[j] = (__bf16)lo[j]; av[4 + j] = (__bf16)hi[j]; }
      acc[rt] = __builtin_amdgcn_mfma_f32_16x16x32_bf16(av, bfrag[C * 2 + ks], acc[rt], 0, 0, 0);
    }
  }
}

// compute chunk C (bf16 data in LDS): 4 row-tiles x 4 k-steps
__device__ __forceinline__ void g1_comp_bf16(const char* ldsbuf, const bf16x8* bfrag,
                                             f32x4* acc, int C, int m, int q)
{
#pragma unroll
  for (int rt = 0; rt < 4; ++rt) {
    const int row = rt * 16 + m;
    const char* rbase = ldsbuf + row * 256;
#pragma unroll
    for (int ks = 0; ks < 4; ++ks) {
      int g0 = ks * 4 + q;
      int s0 = g1_swz16(g0, row);
      U4BF8 a;
      a.u = *(const u32x4*)(rbase + s0 * 16);
      acc[rt] = __builtin_amdgcn_mfma_f32_16x16x32_bf16(a.v, bfrag[C * 4 + ks], acc[rt], 0, 0, 0);
    }
  }
}

__global__ __launch_bounds__(256, 4) void gemm1_kernel(
    const void* __restrict__ x, const __bf16* __restrict__ W1P,
    __bf16* __restrict__ h1, const int* __restrict__ flag)
{
  __shared__ __align__(128) char lds[2][16384];
  const int mode = *flag;
  const int lane = threadIdx.x & 63;
  const int wl   = threadIdx.x >> 6;
  const int c0   = wl * 16;
  const int m    = lane & 15;
  const int q    = lane >> 4;

  const int rowBase = blockIdx.x * G1_ROWS;
  const char* xb = (const char*)x;
  const int RB = mode ? 2048 : 1024;

  // 2-deep prefetch, then the (now coalesced, L2-resident) W1P fragment load
  g1_stage(xb, lds[0], rowBase, 0,        wl, lane, RB);
  g1_stage(xb, lds[1], rowBase, G1_CHUNK, wl, lane, RB);

  bf16x8 bfrag[16];
  const __bf16* wp = W1P + ((size_t)(wl * 16) * 64 + lane) * 8;
#pragma unroll
  for (int t = 0; t < 16; ++t) {
    U4BF8 a; a.u = *(const u32x4*)(wp + (size_t)t * 512);
    bfrag[t] = a.v;
  }

  f32x4 acc[4];
#pragma unroll
  for (int rt = 0; rt < 4; ++rt) acc[rt] = (f32x4){0.f, 0.f, 0.f, 0.f};

  __syncthreads();
  if (mode) {
#pragma unroll
    for (int c = 0; c < 8; ++c) {
      g1_comp_f32(lds[c & 1], bfrag, acc, c, m, q);
      __syncthreads();
      if (c + 2 < 8) g1_stage(xb, lds[c & 1], rowBase, (c + 2) * G1_CHUNK, wl, lane, RB);
    }
  } else {
#pragma unroll
    for (int c = 0; c < 4; ++c) {
      g1_comp_bf16(lds[c & 1], bfrag, acc, c, m, q);
      __syncthreads();
      if (c + 2 < 4) g1_stage(xb, lds[c & 1], rowBase, (c + 2) * G1_CHUNK, wl, lane, RB);
    }
  }

#pragma unroll
  for (int rt = 0; rt < 4; ++rt) {
#pragma unroll
    for (int j = 0; j < 4; ++j) {
      int row = rowBase + rt * 16 + q * 4 + j;
      if (row < N_NODES) h1[(size_t)row * F1 + c0 + m] = (__bf16)acc[rt][j];
    }
  }
}

// ---------------- alpha_s1/alpha_d1 [N,8] ----------------------------------
__global__ __launch_bounds__(256) void alpha1_kernel(
    const __bf16* __restrict__ h1,
    const void* __restrict__ a_src, const void* __restrict__ a_dst,
    float* __restrict__ as, float* __restrict__ ad, const int* __restrict__ flag)
{
  const int mode = *flag;
  int i = blockIdx.x * 256 + threadIdx.x;   // n*8+h
  if (i >= N_NODES * NHEAD) return;
  int h = i & 7;
  const __bf16* hp = h1 + (size_t)(i >> 3) * F1 + h * CH1;
  U4BF8 a; a.u = *(const u32x4*)hp;         // 8 bf16 in one 16B load
  float s = 0.f, d = 0.f;
#pragma unroll
  for (int c = 0; c < CH1; ++c) {
    float hv = (float)a.v[c];
    s += hv * ldmix(a_src, h*CH1 + c, mode);
    d += hv * ldmix(a_dst, h*CH1 + c, mode);
  }
  as[i] = s; ad[i] = d;
}

// ---------------- CSR build, two-level binned -------------------------------
// Phase A: bucket histogram (LDS-aggregated)
__global__ __launch_bounds__(256) void buckhist_kernel(
    const int* __restrict__ ei, int* __restrict__ bh)
{
  __shared__ int h[NBUCK];
  for (int i = threadIdx.x; i < NBUCK; i += 256) h[i] = 0;
  __syncthreads();
  int start = blockIdx.x * 4096;
  for (int i = threadIdx.x; i < 4096; i += 256) {
    int e = start + i;
    if (e < N_EDGES) atomicAdd(&h[ei[N_EDGES + e] >> 8], 1);
  }
  __syncthreads();
  for (int i = threadIdx.x; i < NBUCK; i += 256) {
    int c = h[i];
    if (c) atomicAdd(&bh[i], c);
  }
}

// Phase B-scan: exclusive scan of 391 bucket counts -> bases + cursors
__global__ __launch_bounds__(512) void buckscan_kernel(
    const int* __restrict__ bh, int* __restrict__ bb, int* __restrict__ bcur)
{
  __shared__ int s[512];
  int t = threadIdx.x;
  int v = (t < NBUCK) ? bh[t] : 0;
  s[t] = v;
  __syncthreads();
#pragma unroll
  for (int o = 1; o < 512; o <<= 1) {
    int u = (t >= o) ? s[t - o] : 0;
    __syncthreads();
    s[t] += u;
    __syncthreads();
  }
  if (t < NBUCK) { bb[t] = s[t] - v; bcur[t] = s[t] - v; }
  if (t == NBUCK - 1) bb[NBUCK] = s[t];
}

// Phase B: scatter packed (src<<8 | dst&255) into bucket-ordered `pairs`.
// Per-block LDS histogram -> one global range-claim per bucket -> dense writes.
#define CHB 16384
__global__ __launch_bounds__(256) void buckscatter_kernel(
    const int* __restrict__ ei, int* __restrict__ bcur, int* __restrict__ pairs)
{
  __shared__ int h[NBUCK];
  __shared__ int base[NBUCK];
  for (int i = threadIdx.x; i < NBUCK; i += 256) h[i] = 0;
  __syncthreads();
  int start = blockIdx.x * CHB;
  for (int i = threadIdx.x; i < CHB; i += 256) {
    int e = start + i;
    if (e < N_EDGES) atomicAdd(&h[ei[N_EDGES + e] >> 8], 1);
  }
  __syncthreads();
  for (int i = threadIdx.x; i < NBUCK; i += 256) {
    int c = h[i];
    base[i] = c ? atomicAdd(&bcur[i], c) : 0;
    h[i] = 0;
  }
  __syncthreads();
  for (int i = threadIdx.x; i < CHB; i += 256) {
    int e = start + i;
    if (e < N_EDGES) {
      int dst = ei[N_EDGES + e];
      int src = ei[e];
      int b = dst >> 8;
      int pos = base[b] + atomicAdd(&h[b], 1);
      pairs[pos] = (src << 8) | (dst & 255);
    }
  }
}

// Phase C: one block per bucket: LDS per-dst hist + scan -> off[] AND sorted[]
__global__ __launch_bounds__(256) void csrbuild_kernel(
    const int* __restrict__ bb, const int* __restrict__ pairs,
    int* __restrict__ off, int* __restrict__ sorted)
{
  __shared__ int cnt[256];
  __shared__ int scan[256];
  int b = blockIdx.x;
  int lo = bb[b], hi = bb[b+1];
  int t = threadIdx.x;
  cnt[t] = 0;
  __syncthreads();
  for (int i = lo + t; i < hi; i += 256)
    atomicAdd(&cnt[pairs[i] & 255], 1);
  __syncthreads();
  int v = cnt[t];
  scan[t] = v;
  __syncthreads();
#pragma unroll
  for (int o = 1; o < 256; o <<= 1) {
    int u = (t >= o) ? scan[t - o] : 0;
    __syncthreads();
    scan[t] += u;
    __syncthreads();
  }
  int excl = scan[t] - v;
  int node = b * 256 + t;
  if (node < N_NODES) off[node] = lo + excl;
  if (b == 0 && t == 0) off[N_NODES] = N_EDGES;
  __syncthreads();
  cnt[t] = excl;   // cursor
  __syncthreads();
  for (int i = lo + t; i < hi; i += 256) {
    int p = pairs[i];
    int w = lo + atomicAdd(&cnt[p & 255], 1);
    sorted[w] = p >> 8;
  }
}

// ---------------- layer-1 aggregate: one wave per dst (gather, no atomics) --
// v4: per 64-edge block, lane j computes ALL 8 heads' w for ITS edge,
// stages w into a per-wave LDS strip w[64][8]; per-edge loop is
// bpermute + broadcast ds_read + h1 gather + 2 fma, unroll 16.
__global__ __launch_bounds__(256) void aggregate1_kernel(
    const int* __restrict__ off, const int* __restrict__ sorted,
    const __bf16* __restrict__ h1,
    const float* __restrict__ as, const float* __restrict__ ad,
    const void* __restrict__ b1, __bf16* __restrict__ out1,
    const int* __restrict__ flag)
{
  __shared__ float wlds[4][64][8];
  const int mode = *flag;
  const int lane = threadIdx.x & 63;
  const int wl   = threadIdx.x >> 6;
  int n = blockIdx.x * 4 + wl;
  if (n >= N_NODES) return;
  const int h = lane >> 3;
  const float ad_h = ad[n*NHEAD + h];
  // all 8 ad values for this dst (wave-uniform broadcast loads)
  f32x4 adLo = *(const f32x4*)(ad + (size_t)n * 8);
  f32x4 adHi = *(const f32x4*)(ad + (size_t)n * 8 + 4);

  // self-loop
  float e0 = as[n*NHEAD + h] + ad_h;
  e0 = e0 > 0.f ? e0 : NEG * e0;
  float w0 = __expf(e0);
  float acc = w0 * (float)h1[(size_t)n*F1 + lane];
  float den = w0;

  const int begin = off[n];
  const int cnt   = off[n+1] - begin;
  for (int base = 0; base < cnt; base += 64) {
    int idx = base + lane;
    bool vld = idx < cnt;
    int sv = vld ? sorted[begin + idx] : 0;
    // my edge's attention logits, all 8 heads, vectorized
    f32x4 aLo = *(const f32x4*)(as + (size_t)sv * 8);
    f32x4 aHi = *(const f32x4*)(as + (size_t)sv * 8 + 4);
    f32x4 wLo, wHi;
#pragma unroll
    for (int k = 0; k < 4; ++k) {
      float e  = aLo[k] + adLo[k]; e  = e  > 0.f ? e  : NEG * e;
      float e2 = aHi[k] + adHi[k]; e2 = e2 > 0.f ? e2 : NEG * e2;
      wLo[k] = vld ? __expf(e)  : 0.f;
      wHi[k] = vld ? __expf(e2) : 0.f;
    }
    *(f32x4*)&wlds[wl][lane][0] = wLo;
    *(f32x4*)&wlds[wl][lane][4] = wHi;
    // wave-synchronous: compiler inserts lgkmcnt wait before dependent reads

    int jmax = cnt - base; if (jmax > 64) jmax = 64;
    for (int sub = 0; sub < jmax; sub += 16) {
#pragma unroll
      for (int jj = 0; jj < 16; ++jj) {
        int j = sub + jj;
        int src = __shfl(sv, j);
        float w = wlds[wl][j][h];        // 0 for j >= jmax
        float hv = (float)h1[(size_t)src*F1 + lane];
        acc += w * hv;
        den += w;
      }
    }
  }
  out1[(size_t)n*F1 + lane] = (__bf16)(acc / den + ldmix(b1, lane, mode));
}

// ---------------- h2 = out1 @ W2 (padded to 8), alpha2 ----------------------
__global__ __launch_bounds__(256) void h2_kernel(
    const __bf16* __restrict__ out1, const void* __restrict__ W2,
    const void* __restrict__ a_src2, const void* __restrict__ a_dst2,
    float* __restrict__ h2p, float* __restrict__ as2, float* __restrict__ ad2,
    const int* __restrict__ flag)
{
  const int mode = *flag;
  __shared__ float W2f[F1*C2];
  __shared__ float asw[C2], adw[C2];
  int t = threadIdx.x;
  for (int i = t; i < F1*C2; i += 256) W2f[i] = ldmix(W2, i, mode);
  if (t < C2) { asw[t] = ldmix(a_src2, t, mode); adw[t] = ldmix(a_dst2, t, mode); }
  __syncthreads();
  int n = blockIdx.x * 256 + t;
  if (n >= N_NODES) return;
  float r[F1];
  const u32x4* rp = (const u32x4*)(out1 + (size_t)n * F1);   // 8 x 16B loads
#pragma unroll
  for (int k = 0; k < 8; ++k) {
    U4BF8 tv; tv.u = rp[k];
#pragma unroll
    for (int j = 0; j < 8; ++j) r[k*8 + j] = (float)tv.v[j];
  }
  float s = 0.f, d = 0.f;
#pragma unroll
  for (int c = 0; c < C2; ++c) {
    float acc = 0.f;
#pragma unroll
    for (int j = 0; j < F1; ++j) acc += r[j] * W2f[j*C2 + c];
    h2p[(size_t)n*8 + c] = acc;
    s += acc * asw[c]; d += acc * adw[c];
  }
  h2p[(size_t)n*8 + 7] = 0.f;
  as2[n] = s; ad2[n] = d;
}

// ---------------- layer-2 aggregate: 8 dsts per wave, 8 lanes each ----------
__global__ __launch_bounds__(256) void aggregate2_kernel(
    const int* __restrict__ off, const int* __restrict__ sorted,
    const float* __restrict__ h2p,
    const float* __restrict__ as2, const float* __restrict__ ad2,
    float* __restrict__ logitsP)
{
  const int lane = threadIdx.x & 63;
  const int c    = lane & 7;
  long long wid  = (long long)blockIdx.x * 4 + (threadIdx.x >> 6);
  int n = (int)(wid * 8 + (lane >> 3));
  bool valid = (n < N_NODES);
  if (!valid) n = N_NODES - 1;
  const float ad_n = ad2[n];

  float e0 = as2[n] + ad_n;
  e0 = e0 > 0.f ? e0 : NEG * e0;
  float w0 = __expf(e0);
  float acc = w0 * h2p[(size_t)n*8 + c];   // c==7 slot is 0
  float den = w0;

  const int begin = off[n];
  const int cnt   = off[n+1] - begin;
  for (int base = 0; base < cnt; base += 8) {
    int idx = base + c;
    int sv = (idx < cnt) ? sorted[begin + idx] : 0;
#pragma unroll
    for (int j = 0; j < 8; ++j) {
      int src = __shfl(sv, j, 8);
      float e = as2[src] + ad_n;
      e = e > 0.f ? e : NEG * e;
      float hv = h2p[(size_t)src*8 + c];
      float w = (base + j < cnt) ? __expf(e) : 0.f;
      acc += w * hv;
      den += w;
    }
  }
  if (valid) logitsP[(size_t)n*8 + c] = acc / den;
}

// ---------------- final: + b2, log_softmax -> out ---------------------------
__global__ __launch_bounds__(256) void out_kernel(
    const float* __restrict__ logitsP, const void* __restrict__ b2,
    void* __restrict__ out, const int* __restrict__ flag)
{
  const int mode = *flag;
  int n = blockIdx.x * 256 + threadIdx.x;
  if (n >= N_NODES) return;
  float v[C2];
  float m = -1e30f;
#pragma unroll
  for (int c = 0; c < C2; ++c) {
    v[c] = logitsP[(size_t)n*8 + c] + ldmix(b2, c, mode);
    m = fmaxf(m, v[c]);
  }
  float s = 0.f;
#pragma unroll
  for (int c = 0; c < C2; ++c) s += __expf(v[c] - m);
  float lse = m + __logf(s);
  if (mode) {
    float* op = (float*)out;
#pragma unroll
    for (int c = 0; c < C2; ++c) op[(size_t)n*C2 + c] = v[c] - lse;
  } else {
    __hip_bfloat16* op = (__hip_bfloat16*)out;
#pragma unroll
    for (int c = 0; c < C2; ++c) op[(size_t)n*C2 + c] = __float2bfloat16(v[c] - lse);
  }
}

extern "C" void kernel_launch(void* const* d_in, const int* in_sizes, int n_in,
                              void* d_out, int out_size, void* d_ws, size_t ws_size,
                              hipStream_t stream)
{
  const void* x    = d_in[0];
  const int*  ei   = (const int*)d_in[1];
  const void* W1   = d_in[2];
  const void* as1w = d_in[3];
  const void* ad1w = d_in[4];
  const void* b1   = d_in[5];
  const void* W2   = d_in[6];
  const void* as2w = d_in[7];
  const void* ad2w = d_in[8];
  const void* b2   = d_in[9];

  // ---- workspace layout (float units), total 11.45M floats = 45.8 MB ----
  int*   flag = (int*)d_ws;
  float* ws   = (float*)d_ws + 16;

  float*  A      = ws;                      // region A: [0, 3.2M)
  __bf16* h1b    = (__bf16*)A;              // 6.4M bf16 (dead after aggregate1)
  float*  h2p    = A;                       // 0.8M (aliases dead h1b)
  float*  as2    = A + 800000;              // 0.1M
  float*  ad2    = A + 900000;              // 0.1M
  float*  logitsP= A + 1000000;             // 0.8M (ends 1.8M < 3.2M)

  float*  as1    = ws + 3200000;            // [3.2M, 4.0M)
  float*  ad1    = ws + 4000000;            // [4.0M, 4.8M)
  __bf16* out1   = (__bf16*)(ws + 4800000); // [4.8M, 8.0M) : 6.4M bf16
  int*    pairs  = (int*)(ws + 4800000);    // 3.2M ints, aliases out1 (dead
                                            //   until aggregate1 writes it;
                                            //   pairs dead after csrbuild)
  int*    off    = (int*)(ws + 8000000);    // 100001 ints
  int*    bh     = (int*)(ws + 8110000);    // 391 ints (bucket hist)
  int*    bb     = (int*)(ws + 8112000);    // 392 ints (bucket base)
  int*    bcur   = (int*)(ws + 8114000);    // 391 ints (bucket cursor)
  __bf16* W1P    = (__bf16*)(ws + 8120000); // 32768 bf16 = 16384 floats
                                            //   (ends 8136384 < 8250000)
  int*    sorted = (int*)(ws + 8250000);    // [8.25M, 11.45M) : 3.2M ints

  detect_kernel<<<1, 64, 0, stream>>>((const unsigned int*)x, flag);
  w1pack_kernel<<<16, 256, 0, stream>>>(W1, W1P, flag);
  hipMemsetAsync(bh, 0, NBUCK * sizeof(int), stream);

  gemm1_kernel<<<(N_NODES + G1_ROWS - 1) / G1_ROWS, 256, 0, stream>>>(x, W1P, h1b, flag);
  alpha1_kernel<<<(N_NODES * NHEAD + 255) / 256, 256, 0, stream>>>(h1b, as1w, ad1w, as1, ad1, flag);

  // CSR build (two-level binned; dst-major order == CSR order)
  buckhist_kernel<<<(N_EDGES + 4095) / 4096, 256, 0, stream>>>(ei, bh);
  buckscan_kernel<<<1, 512, 0, stream>>>(bh, bb, bcur);
  buckscatter_kernel<<<(N_EDGES + CHB - 1) / CHB, 256, 0, stream>>>(ei, bcur, pairs);
  csrbuild_kernel<<<NBUCK, 256, 0, stream>>>(bb, pairs, off, sorted);

  aggregate1_kernel<<<(N_NODES + 3) / 4, 256, 0, stream>>>(
      off, sorted, h1b, as1, ad1, b1, out1, flag);

  h2_kernel<<<(N_NODES + 255) / 256, 256, 0, stream>>>(out1, W2, as2w, ad2w, h2p, as2, ad2, flag);

  aggregate2_kernel<<<(N_NODES/8 + 3) / 4 + 1, 256, 0, stream>>>(
      off, sorted, h2p, as2, ad2, logitsP);

  out_kernel<<<(N_NODES + 255) / 256, 256, 0, stream>>>(logitsP, b2, d_out, flag);
}

// Round 7
// 622.869 us; speedup vs baseline: 1.4192x; 1.0236x over previous
//
#include <hip/hip_runtime.h>
#include <hip/hip_bf16.h>

#define N_NODES 100000
#define N_EDGES 3200000
#define F_IN 512
#define NHEAD 8
#define CH1 8
#define F1 64   // NHEAD*CH1
#define C2 7
#define NEG 0.2f
#define NBUCK 391   // dst>>8 : 99999>>8 = 390

typedef __bf16 bf16x8 __attribute__((ext_vector_type(8)));
typedef float  f32x4  __attribute__((ext_vector_type(4)));
typedef unsigned int u32x4 __attribute__((ext_vector_type(4)));

union U4BF8 { u32x4 u; bf16x8 v; };

// load element i of a buffer whose dtype is f32 (mode=1) or bf16 (mode=0)
__device__ __forceinline__ float ldmix(const void* p, size_t i, int f32mode) {
  if (f32mode) return ((const float*)p)[i];
  union { unsigned short u; __bf16 b; } c;
  c.u = ((const unsigned short*)p)[i];
  return (float)c.b;
}

// ---------------- dtype detection: 1 wave -----------------------------------
__global__ void detect_kernel(const unsigned int* __restrict__ x, int* __restrict__ flag) {
  int lane = threadIdx.x & 63;
  unsigned int w = x[lane];
  union { unsigned short u; __bf16 b; } c;
  c.u = (unsigned short)(w & 0xFFFFu);
  float v = (float)c.b;
  bool big = !(fabsf(v) <= 1e6f);   // huge or NaN -> f32 data read as bf16
  unsigned long long m = __ballot(big);
  if (lane == 0) *flag = (m != 0ull) ? 1 : 0;
}

// ---------------- W1 fragment pre-pack (one-time, ~3us) ---------------------
// Layout: W1P[((wl*16+t)*64+lane)*8 + j] = bf16(W1[(32t+q*8+j)*64 + wl*16+m])
__global__ __launch_bounds__(256) void w1pack_kernel(
    const void* __restrict__ W1, __bf16* __restrict__ W1P, const int* __restrict__ flag)
{
  const int mode = *flag;
  int i = blockIdx.x * 256 + threadIdx.x;   // [0, 4096)
  int wl = i >> 10; int t = (i >> 6) & 15; int lane = i & 63;
  int m = lane & 15, q = lane >> 4;
  int c0 = wl * 16;
  bf16x8 tv;
#pragma unroll
  for (int j = 0; j < 8; ++j)
    tv[j] = (__bf16)ldmix(W1, (size_t)(32*t + q*8 + j)*F1 + c0 + m, mode);
  *(bf16x8*)(W1P + (size_t)i * 8) = tv;
}

// ---------------- GEMM: h1[N,64] = x[N,512] @ W1[512,64]  (bf16 out) -------
// round-5 verified pipeline: 16KB chunks (64 rows x 256B), 32KB LDS/block,
// 4 blocks/CU, 2-deep prefetch, __syncthreads between chunks.
// (counted-vmcnt variant shelved after r6 container failure - retry isolated)
#define G1_ROWS 64
#define G1_CHUNK 256   // bytes per row per chunk

__device__ __forceinline__ int g1_swz16(int g, int row) {
  return (g & 8) | ((g ^ row) & 7);
}

// stage one 16KB chunk: LDS dest linear, global source pre-swizzled so
// lds[row][g'] = x[row][swz(g',row)].
__device__ __forceinline__ void g1_stage(const char* xb, char* ldsbuf, int rowBase,
                                         int cByte, int wl, int lane, int rowBytes)
{
#pragma unroll
  for (int i = 0; i < 4; ++i) {
    int G   = ((i * 4 + wl) << 6) + lane;   // granule id in [0,1024)
    int row = G >> 4;                       // 16 granules (256B) per row
    int gp  = G & 15;
    int g   = g1_swz16(gp, row);
    int grow = rowBase + row; if (grow > N_NODES - 1) grow = N_NODES - 1;
    const char* src = xb + (size_t)grow * rowBytes + cByte + g * 16;
    __builtin_amdgcn_global_load_lds(
        (const __attribute__((address_space(1))) void*)src,
        (__attribute__((address_space(3))) void*)(ldsbuf + ((i * 4 + wl) << 10)),
        16, 0, 0);
  }
}

// compute chunk C (f32 data in LDS): 4 row-tiles x 2 k-steps
__device__ __forceinline__ void g1_comp_f32(const char* ldsbuf, const bf16x8* bfrag,
                                            f32x4* acc, int C, int m, int q)
{
#pragma unroll
  for (int rt = 0; rt < 4; ++rt) {
    const int row = rt * 16 + m;
    const char* rbase = ldsbuf + row * 256;
#pragma unroll
    for (int ks = 0; ks < 2; ++ks) {
      int g0 = ks * 8 + q * 2;
      int s0 = g1_swz16(g0, row);
      int s1 = g1_swz16(g0 + 1, row);
      f32x4 lo = *(const f32x4*)(rbase + s0 * 16);
      f32x4 hi = *(const f32x4*)(rbase + s1 * 16);
      bf16x8 av;
#pragma unroll
      for (int j = 0; j < 4; ++j) { av[j] = (__bf16)lo[j]; av[4 + j] = (__bf16)hi[j]; }
      acc[rt] = __builtin_amdgcn_mfma_f32_16x16x32_bf16(av, bfrag[C * 2 + ks], acc[rt], 0, 0, 0);
    }
  }
}

// compute chunk C (bf16 data in LDS): 4 row-tiles x 4 k-steps
__device__ __forceinline__ void g1_comp_bf16(const char* ldsbuf, const bf16x8* bfrag,
                                             f32x4* acc, int C, int m, int q)
{
#pragma unroll
  for (int rt = 0; rt < 4; ++rt) {
    const int row = rt * 16 + m;
    const char* rbase = ldsbuf + row * 256;
#pragma unroll
    for (int ks = 0; ks < 4; ++ks) {
      int g0 = ks * 4 + q;
      int s0 = g1_swz16(g0, row);
      U4BF8 a;
      a.u = *(const u32x4*)(rbase + s0 * 16);
      acc[rt] = __builtin_amdgcn_mfma_f32_16x16x32_bf16(a.v, bfrag[C * 4 + ks], acc[rt], 0, 0, 0);
    }
  }
}

__global__ __launch_bounds__(256, 4) void gemm1_kernel(
    const void* __restrict__ x, const __bf16* __restrict__ W1P,
    __bf16* __restrict__ h1, const int* __restrict__ flag)
{
  __shared__ __align__(128) char lds[2][16384];
  const int mode = *flag;
  const int lane = threadIdx.x & 63;
  const int wl   = threadIdx.x >> 6;
  const int c0   = wl * 16;
  const int m    = lane & 15;
  const int q    = lane >> 4;

  const int rowBase = blockIdx.x * G1_ROWS;
  const char* xb = (const char*)x;
  const int RB = mode ? 2048 : 1024;

  // 2-deep prefetch, then the coalesced L2-resident W1P fragment load
  g1_stage(xb, lds[0], rowBase, 0,        wl, lane, RB);
  g1_stage(xb, lds[1], rowBase, G1_CHUNK, wl, lane, RB);

  bf16x8 bfrag[16];
  const __bf16* wp = W1P + ((size_t)(wl * 16) * 64 + lane) * 8;
#pragma unroll
  for (int t = 0; t < 16; ++t) {
    U4BF8 a; a.u = *(const u32x4*)(wp + (size_t)t * 512);
    bfrag[t] = a.v;
  }

  f32x4 acc[4];
#pragma unroll
  for (int rt = 0; rt < 4; ++rt) acc[rt] = (f32x4){0.f, 0.f, 0.f, 0.f};

  __syncthreads();
  if (mode) {
#pragma unroll
    for (int c = 0; c < 8; ++c) {
      g1_comp_f32(lds[c & 1], bfrag, acc, c, m, q);
      __syncthreads();
      if (c + 2 < 8) g1_stage(xb, lds[c & 1], rowBase, (c + 2) * G1_CHUNK, wl, lane, RB);
    }
  } else {
#pragma unroll
    for (int c = 0; c < 4; ++c) {
      g1_comp_bf16(lds[c & 1], bfrag, acc, c, m, q);
      __syncthreads();
      if (c + 2 < 4) g1_stage(xb, lds[c & 1], rowBase, (c + 2) * G1_CHUNK, wl, lane, RB);
    }
  }

#pragma unroll
  for (int rt = 0; rt < 4; ++rt) {
#pragma unroll
    for (int j = 0; j < 4; ++j) {
      int row = rowBase + rt * 16 + q * 4 + j;
      if (row < N_NODES) h1[(size_t)row * F1 + c0 + m] = (__bf16)acc[rt][j];
    }
  }
}

// ---------------- alpha_s1/alpha_d1 [N,8] ----------------------------------
__global__ __launch_bounds__(256) void alpha1_kernel(
    const __bf16* __restrict__ h1,
    const void* __restrict__ a_src, const void* __restrict__ a_dst,
    float* __restrict__ as, float* __restrict__ ad, const int* __restrict__ flag)
{
  const int mode = *flag;
  int i = blockIdx.x * 256 + threadIdx.x;   // n*8+h
  if (i >= N_NODES * NHEAD) return;
  int h = i & 7;
  const __bf16* hp = h1 + (size_t)(i >> 3) * F1 + h * CH1;
  U4BF8 a; a.u = *(const u32x4*)hp;         // 8 bf16 in one 16B load
  float s = 0.f, d = 0.f;
#pragma unroll
  for (int c = 0; c < CH1; ++c) {
    float hv = (float)a.v[c];
    s += hv * ldmix(a_src, h*CH1 + c, mode);
    d += hv * ldmix(a_dst, h*CH1 + c, mode);
  }
  as[i] = s; ad[i] = d;
}

// ---------------- CSR build, two-level binned -------------------------------
// Phase A: bucket histogram (LDS-aggregated)
__global__ __launch_bounds__(256) void buckhist_kernel(
    const int* __restrict__ ei, int* __restrict__ bh)
{
  __shared__ int h[NBUCK];
  for (int i = threadIdx.x; i < NBUCK; i += 256) h[i] = 0;
  __syncthreads();
  int start = blockIdx.x * 4096;
  for (int i = threadIdx.x; i < 4096; i += 256) {
    int e = start + i;
    if (e < N_EDGES) atomicAdd(&h[ei[N_EDGES + e] >> 8], 1);
  }
  __syncthreads();
  for (int i = threadIdx.x; i < NBUCK; i += 256) {
    int c = h[i];
    if (c) atomicAdd(&bh[i], c);
  }
}

// Phase B-scan: exclusive scan of 391 bucket counts -> bases + cursors
__global__ __launch_bounds__(512) void buckscan_kernel(
    const int* __restrict__ bh, int* __restrict__ bb, int* __restrict__ bcur)
{
  __shared__ int s[512];
  int t = threadIdx.x;
  int v = (t < NBUCK) ? bh[t] : 0;
  s[t] = v;
  __syncthreads();
#pragma unroll
  for (int o = 1; o < 512; o <<= 1) {
    int u = (t >= o) ? s[t - o] : 0;
    __syncthreads();
    s[t] += u;
    __syncthreads();
  }
  if (t < NBUCK) { bb[t] = s[t] - v; bcur[t] = s[t] - v; }
  if (t == NBUCK - 1) bb[NBUCK] = s[t];
}

// Phase B: scatter packed (src<<8 | dst&255) into bucket-ordered `pairs`.
#define CHB 16384
__global__ __launch_bounds__(256) void buckscatter_kernel(
    const int* __restrict__ ei, int* __restrict__ bcur, int* __restrict__ pairs)
{
  __shared__ int h[NBUCK];
  __shared__ int base[NBUCK];
  for (int i = threadIdx.x; i < NBUCK; i += 256) h[i] = 0;
  __syncthreads();
  int start = blockIdx.x * CHB;
  for (int i = threadIdx.x; i < CHB; i += 256) {
    int e = start + i;
    if (e < N_EDGES) atomicAdd(&h[ei[N_EDGES + e] >> 8], 1);
  }
  __syncthreads();
  for (int i = threadIdx.x; i < NBUCK; i += 256) {
    int c = h[i];
    base[i] = c ? atomicAdd(&bcur[i], c) : 0;
    h[i] = 0;
  }
  __syncthreads();
  for (int i = threadIdx.x; i < CHB; i += 256) {
    int e = start + i;
    if (e < N_EDGES) {
      int dst = ei[N_EDGES + e];
      int src = ei[e];
      int b = dst >> 8;
      int pos = base[b] + atomicAdd(&h[b], 1);
      pairs[pos] = (src << 8) | (dst & 255);
    }
  }
}

// Phase C: one block per bucket: LDS per-dst hist + scan -> off[] AND sorted[]
__global__ __launch_bounds__(256) void csrbuild_kernel(
    const int* __restrict__ bb, const int* __restrict__ pairs,
    int* __restrict__ off, int* __restrict__ sorted)
{
  __shared__ int cnt[256];
  __shared__ int scan[256];
  int b = blockIdx.x;
  int lo = bb[b], hi = bb[b+1];
  int t = threadIdx.x;
  cnt[t] = 0;
  __syncthreads();
  for (int i = lo + t; i < hi; i += 256)
    atomicAdd(&cnt[pairs[i] & 255], 1);
  __syncthreads();
  int v = cnt[t];
  scan[t] = v;
  __syncthreads();
#pragma unroll
  for (int o = 1; o < 256; o <<= 1) {
    int u = (t >= o) ? scan[t - o] : 0;
    __syncthreads();
    scan[t] += u;
    __syncthreads();
  }
  int excl = scan[t] - v;
  int node = b * 256 + t;
  if (node < N_NODES) off[node] = lo + excl;
  if (b == 0 && t == 0) off[N_NODES] = N_EDGES;
  __syncthreads();
  cnt[t] = excl;   // cursor
  __syncthreads();
  for (int i = lo + t; i < hi; i += 256) {
    int p = pairs[i];
    int w = lo + atomicAdd(&cnt[p & 255], 1);
    sorted[w] = p >> 8;
  }
}

// ---------------- layer-1 aggregate: one wave per dst (gather, no atomics) --
// v4: per 64-edge block, lane j computes ALL 8 heads' w for ITS edge,
// stages w into a per-wave LDS strip w[64][8]; per-edge loop is
// bpermute + broadcast ds_read + h1 gather + 2 fma, unroll 16.
__global__ __launch_bounds__(256) void aggregate1_kernel(
    const int* __restrict__ off, const int* __restrict__ sorted,
    const __bf16* __restrict__ h1,
    const float* __restrict__ as, const float* __restrict__ ad,
    const void* __restrict__ b1, __bf16* __restrict__ out1,
    const int* __restrict__ flag)
{
  __shared__ float wlds[4][64][8];
  const int mode = *flag;
  const int lane = threadIdx.x & 63;
  const int wl   = threadIdx.x >> 6;
  int n = blockIdx.x * 4 + wl;
  if (n >= N_NODES) return;
  const int h = lane >> 3;
  const float ad_h = ad[n*NHEAD + h];
  // all 8 ad values for this dst (wave-uniform broadcast loads)
  f32x4 adLo = *(const f32x4*)(ad + (size_t)n * 8);
  f32x4 adHi = *(const f32x4*)(ad + (size_t)n * 8 + 4);

  // self-loop
  float e0 = as[n*NHEAD + h] + ad_h;
  e0 = e0 > 0.f ? e0 : NEG * e0;
  float w0 = __expf(e0);
  float acc = w0 * (float)h1[(size_t)n*F1 + lane];
  float den = w0;

  const int begin = off[n];
  const int cnt   = off[n+1] - begin;
  for (int base = 0; base < cnt; base += 64) {
    int idx = base + lane;
    bool vld = idx < cnt;
    int sv = vld ? sorted[begin + idx] : 0;
    // my edge's attention logits, all 8 heads, vectorized
    f32x4 aLo = *(const f32x4*)(as + (size_t)sv * 8);
    f32x4 aHi = *(const f32x4*)(as + (size_t)sv * 8 + 4);
    f32x4 wLo, wHi;
#pragma unroll
    for (int k = 0; k < 4; ++k) {
      float e  = aLo[k] + adLo[k]; e  = e  > 0.f ? e  : NEG * e;
      float e2 = aHi[k] + adHi[k]; e2 = e2 > 0.f ? e2 : NEG * e2;
      wLo[k] = vld ? __expf(e)  : 0.f;
      wHi[k] = vld ? __expf(e2) : 0.f;
    }
    *(f32x4*)&wlds[wl][lane][0] = wLo;
    *(f32x4*)&wlds[wl][lane][4] = wHi;
    // wave-synchronous: compiler inserts lgkmcnt wait before dependent reads

    int jmax = cnt - base; if (jmax > 64) jmax = 64;
    for (int sub = 0; sub < jmax; sub += 16) {
#pragma unroll
      for (int jj = 0; jj < 16; ++jj) {
        int j = sub + jj;
        int src = __shfl(sv, j);
        float w = wlds[wl][j][h];        // 0 for j >= jmax
        float hv = (float)h1[(size_t)src*F1 + lane];
        acc += w * hv;
        den += w;
      }
    }
  }
  out1[(size_t)n*F1 + lane] = (__bf16)(acc / den + ldmix(b1, lane, mode));
}

// ---------------- h2 = out1 @ W2 (padded to 8), alpha2 ----------------------
__global__ __launch_bounds__(256) void h2_kernel(
    const __bf16* __restrict__ out1, const void* __restrict__ W2,
    const void* __restrict__ a_src2, const void* __restrict__ a_dst2,
    float* __restrict__ h2p, float* __restrict__ as2, float* __restrict__ ad2,
    const int* __restrict__ flag)
{
  const int mode = *flag;
  __shared__ float W2f[F1*C2];
  __shared__ float asw[C2], adw[C2];
  int t = threadIdx.x;
  for (int i = t; i < F1*C2; i += 256) W2f[i] = ldmix(W2, i, mode);
  if (t < C2) { asw[t] = ldmix(a_src2, t, mode); adw[t] = ldmix(a_dst2, t, mode); }
  __syncthreads();
  int n = blockIdx.x * 256 + t;
  if (n >= N_NODES) return;
  float r[F1];
  const u32x4* rp = (const u32x4*)(out1 + (size_t)n * F1);   // 8 x 16B loads
#pragma unroll
  for (int k = 0; k < 8; ++k) {
    U4BF8 tv; tv.u = rp[k];
#pragma unroll
    for (int j = 0; j < 8; ++j) r[k*8 + j] = (float)tv.v[j];
  }
  float s = 0.f, d = 0.f;
#pragma unroll
  for (int c = 0; c < C2; ++c) {
    float acc = 0.f;
#pragma unroll
    for (int j = 0; j < F1; ++j) acc += r[j] * W2f[j*C2 + c];
    h2p[(size_t)n*8 + c] = acc;
    s += acc * asw[c]; d += acc * adw[c];
  }
  h2p[(size_t)n*8 + 7] = 0.f;
  as2[n] = s; ad2[n] = d;
}

// ---------------- layer-2 aggregate + log_softmax (fused out) ---------------
// v2: owner-lane computes each edge's w ONCE (was 8x duplicated across the
// dst-group) and broadcasts via shfl width 8 -- bit-identical values. Fused
// b2 + log_softmax via 8-lane butterflies; writes final output directly.
__global__ __launch_bounds__(256) void aggregate2_kernel(
    const int* __restrict__ off, const int* __restrict__ sorted,
    const float* __restrict__ h2p,
    const float* __restrict__ as2, const float* __restrict__ ad2,
    const void* __restrict__ b2, void* __restrict__ outp,
    const int* __restrict__ flag)
{
  const int mode = *flag;
  const int lane = threadIdx.x & 63;
  const int c    = lane & 7;
  long long wid  = (long long)blockIdx.x * 4 + (threadIdx.x >> 6);
  int n = (int)(wid * 8 + (lane >> 3));
  bool valid = (n < N_NODES);
  if (!valid) n = N_NODES - 1;
  const float ad_n = ad2[n];

  float e0 = as2[n] + ad_n;
  e0 = e0 > 0.f ? e0 : NEG * e0;
  float w0 = __expf(e0);
  float acc = w0 * h2p[(size_t)n*8 + c];   // c==7 slot is 0
  float den = w0;

  const int begin = off[n];
  const int cnt   = off[n+1] - begin;
  for (int base = 0; base < cnt; base += 8) {
    int idx = base + c;
    bool vld = idx < cnt;
    int sv = vld ? sorted[begin + idx] : 0;
    // owner lane computes its edge's weight once
    float e = as2[sv] + ad_n;
    e = e > 0.f ? e : NEG * e;
    float wo = vld ? __expf(e) : 0.f;
#pragma unroll
    for (int j = 0; j < 8; ++j) {
      int src  = __shfl(sv, j, 8);
      float w  = __shfl(wo, j, 8);
      float hv = h2p[(size_t)src*8 + c];
      acc += w * hv;
      den += w;
    }
  }

  // logits + b2, then log_softmax over c=0..6 within the 8-lane group
  float vv = acc / den + ldmix(b2, (c < 7) ? c : 0, mode);
  float mv = (c < 7) ? vv : -1e30f;
#pragma unroll
  for (int o = 1; o < 8; o <<= 1) mv = fmaxf(mv, __shfl_xor(mv, o, 8));
  float ex = (c < 7) ? __expf(vv - mv) : 0.f;
  float sum = ex;
#pragma unroll
  for (int o = 1; o < 8; o <<= 1) sum += __shfl_xor(sum, o, 8);
  float res = vv - (mv + __logf(sum));
  if (valid && c < 7) {
    if (mode) ((float*)outp)[(size_t)n*C2 + c] = res;
    else      ((__hip_bfloat16*)outp)[(size_t)n*C2 + c] = __float2bfloat16(res);
  }
}

extern "C" void kernel_launch(void* const* d_in, const int* in_sizes, int n_in,
                              void* d_out, int out_size, void* d_ws, size_t ws_size,
                              hipStream_t stream)
{
  const void* x    = d_in[0];
  const int*  ei   = (const int*)d_in[1];
  const void* W1   = d_in[2];
  const void* as1w = d_in[3];
  const void* ad1w = d_in[4];
  const void* b1   = d_in[5];
  const void* W2   = d_in[6];
  const void* as2w = d_in[7];
  const void* ad2w = d_in[8];
  const void* b2   = d_in[9];

  // ---- workspace layout (float units), total 11.45M floats = 45.8 MB ----
  int*   flag = (int*)d_ws;
  float* ws   = (float*)d_ws + 16;

  float*  A      = ws;                      // region A: [0, 3.2M)
  __bf16* h1b    = (__bf16*)A;              // 6.4M bf16 (dead after aggregate1)
  float*  h2p    = A;                       // 0.8M (aliases dead h1b)
  float*  as2    = A + 800000;              // 0.1M
  float*  ad2    = A + 900000;              // 0.1M

  float*  as1    = ws + 3200000;            // [3.2M, 4.0M)
  float*  ad1    = ws + 4000000;            // [4.0M, 4.8M)
  __bf16* out1   = (__bf16*)(ws + 4800000); // [4.8M, 8.0M) : 6.4M bf16
  int*    pairs  = (int*)(ws + 4800000);    // 3.2M ints, aliases out1 (dead
                                            //   until aggregate1 writes it;
                                            //   pairs dead after csrbuild)
  int*    off    = (int*)(ws + 8000000);    // 100001 ints
  int*    bh     = (int*)(ws + 8110000);    // 391 ints (bucket hist)
  int*    bb     = (int*)(ws + 8112000);    // 392 ints (bucket base)
  int*    bcur   = (int*)(ws + 8114000);    // 391 ints (bucket cursor)
  __bf16* W1P    = (__bf16*)(ws + 8120000); // 32768 bf16 = 16384 floats
  int*    sorted = (int*)(ws + 8250000);    // [8.25M, 11.45M) : 3.2M ints

  detect_kernel<<<1, 64, 0, stream>>>((const unsigned int*)x, flag);
  w1pack_kernel<<<16, 256, 0, stream>>>(W1, W1P, flag);
  hipMemsetAsync(bh, 0, NBUCK * sizeof(int), stream);

  gemm1_kernel<<<(N_NODES + G1_ROWS - 1) / G1_ROWS, 256, 0, stream>>>(x, W1P, h1b, flag);
  alpha1_kernel<<<(N_NODES * NHEAD + 255) / 256, 256, 0, stream>>>(h1b, as1w, ad1w, as1, ad1, flag);

  // CSR build (two-level binned; dst-major order == CSR order)
  buckhist_kernel<<<(N_EDGES + 4095) / 4096, 256, 0, stream>>>(ei, bh);
  buckscan_kernel<<<1, 512, 0, stream>>>(bh, bb, bcur);
  buckscatter_kernel<<<(N_EDGES + CHB - 1) / CHB, 256, 0, stream>>>(ei, bcur, pairs);
  csrbuild_kernel<<<NBUCK, 256, 0, stream>>>(bb, pairs, off, sorted);

  aggregate1_kernel<<<(N_NODES + 3) / 4, 256, 0, stream>>>(
      off, sorted, h1b, as1, ad1, b1, out1, flag);

  h2_kernel<<<(N_NODES + 255) / 256, 256, 0, stream>>>(out1, W2, as2w, ad2w, h2p, as2, ad2, flag);

  aggregate2_kernel<<<(N_NODES/8 + 3) / 4 + 1, 256, 0, stream>>>(
      off, sorted, h2p, as2, ad2, b2, d_out, flag);
}